// Round 1
// baseline (6247.615 us; speedup 1.0000x reference)
//
#include <hip/hip_runtime.h>
#include <hip/hip_bf16.h>

#define B_    4
#define S_    8192
#define D_    1024
#define H_    8
#define DKV_  128
#define SEG_  512
#define NSEG_ 16
#define BS_   (B_ * S_)   // 32768

// ---------------------------------------------------------------------------
// K1: Y[m,n] = A[m,:] @ W[:,n] + bias[n].  M=32768, N=1024, K=1024.
// 128x128 tile, BK=16, 256 threads, 8x8 per thread, f32.
// ---------------------------------------------------------------------------
__global__ __launch_bounds__(256) void sgemm_bias(
    const float* __restrict__ A, const float* __restrict__ W,
    const float* __restrict__ bias, float* __restrict__ Y) {
  __shared__ float As[16][132];   // [k][m] (transposed store)
  __shared__ float Bs[16][132];   // [k][n]
  const int t  = threadIdx.x;
  const int m0 = blockIdx.x * 128;
  const int n0 = blockIdx.y * 128;
  const int tm = t >> 4, tn = t & 15;
  float acc[8][8] = {};
  for (int k0 = 0; k0 < 1024; k0 += 16) {
#pragma unroll
    for (int rep = 0; rep < 2; ++rep) {
      int lin = t + rep * 256;            // 0..511
      // A tile: 128 rows x 16 k  (512 float4)
      int arow = lin >> 2;
      int kq   = lin & 3;
      float4 av = *(const float4*)&A[(size_t)(m0 + arow) * 1024 + k0 + kq * 4];
      As[kq * 4 + 0][arow] = av.x;
      As[kq * 4 + 1][arow] = av.y;
      As[kq * 4 + 2][arow] = av.z;
      As[kq * 4 + 3][arow] = av.w;
      // B tile: 16 rows x 128 n  (512 float4)
      int brow = lin >> 5;
      int cq   = lin & 31;
      *(float4*)&Bs[brow][cq * 4] =
          *(const float4*)&W[(size_t)(k0 + brow) * 1024 + n0 + cq * 4];
    }
    __syncthreads();
#pragma unroll
    for (int kk = 0; kk < 16; ++kk) {
      float a[8], bb[8];
      *(float4*)&a[0]  = *(const float4*)&As[kk][tm * 8];
      *(float4*)&a[4]  = *(const float4*)&As[kk][tm * 8 + 4];
      *(float4*)&bb[0] = *(const float4*)&Bs[kk][tn * 8];
      *(float4*)&bb[4] = *(const float4*)&Bs[kk][tn * 8 + 4];
#pragma unroll
      for (int i = 0; i < 8; ++i)
#pragma unroll
        for (int j = 0; j < 8; ++j)
          acc[i][j] = fmaf(a[i], bb[j], acc[i][j]);
    }
    __syncthreads();
  }
#pragma unroll
  for (int i = 0; i < 8; ++i) {
    size_t gm = (size_t)(m0 + tm * 8 + i);
#pragma unroll
    for (int j = 0; j < 8; j += 4) {
      float4 o;
      o.x = acc[i][j + 0] + bias[n0 + tn * 8 + j + 0];
      o.y = acc[i][j + 1] + bias[n0 + tn * 8 + j + 1];
      o.z = acc[i][j + 2] + bias[n0 + tn * 8 + j + 2];
      o.w = acc[i][j + 3] + bias[n0 + tn * 8 + j + 3];
      *(float4*)&Y[gm * 1024 + n0 + tn * 8 + j] = o;
    }
  }
}

// ---------------------------------------------------------------------------
// K2: per-(seg,b,h) segment state: Skv[dk,dv] = sum_l sk[l,dk]*v[l,dv],
//     zsum[dk] = (sum_l sk[l,dk]) * SEG,  sk = elu(k)+1.
// grid 512 = NSEG*B*H, 256 threads, 8x8 outputs/thread.
// ---------------------------------------------------------------------------
__global__ __launch_bounds__(256) void seg_kv(
    const float* __restrict__ Kb, const float* __restrict__ Vb,
    float* __restrict__ Mem, float* __restrict__ Zs) {
  __shared__ float sk[16][132];
  __shared__ float sv[16][132];
  const int bx  = blockIdx.x;
  const int seg = bx >> 5;
  const int bh  = bx & 31;          // b*8+h
  const int b   = bh >> 3, h = bh & 7;
  const int t   = threadIdx.x;
  const int tr  = t >> 4, tc = t & 15;  // dk0 = tr*8, dv0 = tc*8
  float acc[8][8] = {};
  float zacc = 0.f;
  const size_t rowbase = (size_t)b * S_ + (size_t)seg * SEG_;
  for (int l0 = 0; l0 < SEG_; l0 += 16) {
    __syncthreads();   // protect LDS from previous iteration's readers
#pragma unroll
    for (int rep = 0; rep < 2; ++rep) {
      int lin = t + rep * 256;     // 0..511
      int row = lin >> 5;          // 0..15
      int dqc = lin & 31;
      size_t g = (rowbase + l0 + row) * 1024 + h * 128 + dqc * 4;
      float4 kv = *(const float4*)&Kb[g];
      float4 vv = *(const float4*)&Vb[g];
      sk[row][dqc * 4 + 0] = kv.x > 0.f ? kv.x + 1.f : __expf(kv.x);
      sk[row][dqc * 4 + 1] = kv.y > 0.f ? kv.y + 1.f : __expf(kv.y);
      sk[row][dqc * 4 + 2] = kv.z > 0.f ? kv.z + 1.f : __expf(kv.z);
      sk[row][dqc * 4 + 3] = kv.w > 0.f ? kv.w + 1.f : __expf(kv.w);
      *(float4*)&sv[row][dqc * 4] = vv;
    }
    __syncthreads();
#pragma unroll
    for (int l = 0; l < 16; ++l) {
      float a[8], v[8];
      *(float4*)&a[0] = *(const float4*)&sk[l][tr * 8];
      *(float4*)&a[4] = *(const float4*)&sk[l][tr * 8 + 4];
      *(float4*)&v[0] = *(const float4*)&sv[l][tc * 8];
      *(float4*)&v[4] = *(const float4*)&sv[l][tc * 8 + 4];
#pragma unroll
      for (int i = 0; i < 8; ++i)
#pragma unroll
        for (int j = 0; j < 8; ++j)
          acc[i][j] = fmaf(a[i], v[j], acc[i][j]);
    }
    if (t < 128) {
#pragma unroll
      for (int l = 0; l < 16; ++l) zacc += sk[l][t];
    }
  }
  const size_t base = ((size_t)seg * 32 + bh) * 16384;
#pragma unroll
  for (int i = 0; i < 8; ++i)
#pragma unroll
    for (int j = 0; j < 8; j += 4) {
      float4 o;
      o.x = acc[i][j + 0]; o.y = acc[i][j + 1];
      o.z = acc[i][j + 2]; o.w = acc[i][j + 3];
      *(float4*)&Mem[base + (size_t)(tr * 8 + i) * 128 + tc * 8 + j] = o;
    }
  if (t < 128) Zs[((size_t)seg * 32 + bh) * 128 + t] = zacc * (float)SEG_;
}

// ---------------------------------------------------------------------------
// K3: in-place inclusive prefix over seg axis for Mem and Zs.
// grid 512: bh = bx&31, part = bx>>5 (each part: 4 of the 64 j-groups).
// ---------------------------------------------------------------------------
__global__ __launch_bounds__(256) void prefix_scan(
    float* __restrict__ Mem, float* __restrict__ Zs) {
  const int bx = blockIdx.x;
  const int bh = bx & 31;
  const int part = bx >> 5;   // 0..15
  const int t = threadIdx.x;
  for (int jj = 0; jj < 4; ++jj) {
    size_t flat = ((size_t)part * 4 + jj) * 256 + t;   // 0..16383
    float run = 0.f;
#pragma unroll
    for (int seg = 0; seg < NSEG_; ++seg) {
      size_t idx = ((size_t)seg * 32 + bh) * 16384 + flat;
      run += Mem[idx];
      Mem[idx] = run;
    }
  }
  if (part == 0 && t < 128) {
    float run = 0.f;
#pragma unroll
    for (int seg = 0; seg < NSEG_; ++seg) {
      size_t idx = ((size_t)seg * 32 + bh) * 128 + t;
      run += Zs[idx];
      Zs[idx] = run;
    }
  }
}

// ---------------------------------------------------------------------------
// K4: per (b, seg, rowblk of 64 q-rows): for all 8 heads, flash-style local
// softmax attention + linear-memory retrieval, blended head-mean -> out.
// 256 threads. Ownership: rq=t>>4 -> rows rq*4..+3, dq=t&15 -> dv dq*8..+7.
// LDS ~117 KB -> 1 block/CU.
// ---------------------------------------------------------------------------
__global__ void attn_blend(
    const float* __restrict__ Qb, const float* __restrict__ Kb,
    const float* __restrict__ Vb, const float* __restrict__ Mem,
    const float* __restrict__ Zs, const float* __restrict__ beta,
    float* __restrict__ Out) {
  __shared__ float Qs[64][132];
  __shared__ float Ks[64][132];   // key chunk; reused for Mem chunks
  __shared__ float Vs[64][132];
  __shared__ float Ss[64][65];    // score block / p
  __shared__ float mrow[64], lrow[64], fscale[64], dnm[64];
  __shared__ float zl[128];

  const int t   = threadIdx.x;
  const int rb  = blockIdx.x;    // 0..7
  const int seg = blockIdx.y;    // 0..15
  const int b   = blockIdx.z;    // 0..3
  const int rq  = t >> 4;        // 0..15
  const int dq  = t & 15;        // 0..15
  const float scale = 0.08838834764831845f;  // 1/sqrt(128)
  const float bsig  = 1.f / (1.f + __expf(-beta[0]));
  const float wmem  = bsig * 0.125f;
  const float wdot  = (1.f - bsig) * 0.125f;

  float accum[4][8] = {};
  const size_t segrow = (size_t)b * S_ + (size_t)seg * SEG_;

  for (int h = 0; h < H_; ++h) {
    __syncthreads();   // protect Qs/zl from previous head's readers
    // stage Q rows (64 x 128)
#pragma unroll
    for (int rep = 0; rep < 8; ++rep) {
      int lin = t + rep * 256;       // 0..2047
      int row = lin >> 5, c = lin & 31;
      *(float4*)&Qs[row][c * 4] =
          *(const float4*)&Qb[(segrow + rb * 64 + row) * 1024 + h * 128 + c * 4];
    }
    if (t < 64) { mrow[t] = -1e30f; lrow[t] = 0.f; }
    if (t < 128) zl[t] = Zs[((size_t)seg * 32 + b * 8 + h) * 128 + t];
    float o[4][8] = {};
    __syncthreads();

    // ---- local softmax attention over 8 key chunks of 64 ----
    for (int c = 0; c < 8; ++c) {
#pragma unroll
      for (int rep = 0; rep < 8; ++rep) {
        int lin = t + rep * 256;
        int row = lin >> 5, cc = lin & 31;
        size_t g = (segrow + c * 64 + row) * 1024 + h * 128 + cc * 4;
        *(float4*)&Ks[row][cc * 4] = *(const float4*)&Kb[g];
        *(float4*)&Vs[row][cc * 4] = *(const float4*)&Vb[g];
      }
      __syncthreads();
      // S block 64x64: thread does 4x4
      float sacc[4][4] = {};
      for (int d = 0; d < 128; d += 4) {
        float4 q0 = *(const float4*)&Qs[rq * 4 + 0][d];
        float4 q1 = *(const float4*)&Qs[rq * 4 + 1][d];
        float4 q2 = *(const float4*)&Qs[rq * 4 + 2][d];
        float4 q3 = *(const float4*)&Qs[rq * 4 + 3][d];
        float4 k0 = *(const float4*)&Ks[dq * 4 + 0][d];
        float4 k1 = *(const float4*)&Ks[dq * 4 + 1][d];
        float4 k2 = *(const float4*)&Ks[dq * 4 + 2][d];
        float4 k3 = *(const float4*)&Ks[dq * 4 + 3][d];
        float4 qa[4] = {q0, q1, q2, q3};
        float4 ka[4] = {k0, k1, k2, k3};
#pragma unroll
        for (int i = 0; i < 4; ++i)
#pragma unroll
          for (int j = 0; j < 4; ++j) {
            sacc[i][j] = fmaf(qa[i].x, ka[j].x, sacc[i][j]);
            sacc[i][j] = fmaf(qa[i].y, ka[j].y, sacc[i][j]);
            sacc[i][j] = fmaf(qa[i].z, ka[j].z, sacc[i][j]);
            sacc[i][j] = fmaf(qa[i].w, ka[j].w, sacc[i][j]);
          }
      }
#pragma unroll
      for (int i = 0; i < 4; ++i)
#pragma unroll
        for (int j = 0; j < 4; ++j)
          Ss[rq * 4 + i][dq * 4 + j] = sacc[i][j] * scale;
      __syncthreads();
      // online softmax row update (wave 0)
      if (t < 64) {
        float mx = -1e30f;
#pragma unroll
        for (int j = 0; j < 64; ++j) mx = fmaxf(mx, Ss[t][j]);
        float mnew = fmaxf(mrow[t], mx);
        float f = __expf(mrow[t] - mnew);
        float ps = 0.f;
#pragma unroll
        for (int j = 0; j < 64; ++j) {
          float p = __expf(Ss[t][j] - mnew);
          Ss[t][j] = p;
          ps += p;
        }
        lrow[t] = lrow[t] * f + ps;
        mrow[t] = mnew;
        fscale[t] = f;
      }
      __syncthreads();
      // rescale o, then PV accumulate
#pragma unroll
      for (int i = 0; i < 4; ++i) {
        float f = fscale[rq * 4 + i];
#pragma unroll
        for (int j = 0; j < 8; ++j) o[i][j] *= f;
      }
      for (int m = 0; m < 64; ++m) {
        float p0 = Ss[rq * 4 + 0][m];
        float p1 = Ss[rq * 4 + 1][m];
        float p2 = Ss[rq * 4 + 2][m];
        float p3 = Ss[rq * 4 + 3][m];
        float4 v0 = *(const float4*)&Vs[m][dq * 8];
        float4 v1 = *(const float4*)&Vs[m][dq * 8 + 4];
        float vv[8] = {v0.x, v0.y, v0.z, v0.w, v1.x, v1.y, v1.z, v1.w};
        float pp[4] = {p0, p1, p2, p3};
#pragma unroll
        for (int i = 0; i < 4; ++i)
#pragma unroll
          for (int j = 0; j < 8; ++j)
            o[i][j] = fmaf(pp[i], vv[j], o[i][j]);
      }
      __syncthreads();  // Ss/Ks/Vs free for next chunk
    }

    // ---- retrieval denominator: sq . z per row (wave 0) ----
    if (t < 64) {
      float s = 0.f;
      for (int dk = 0; dk < 128; ++dk) {
        float qv = Qs[t][dk];
        float sq = qv > 0.f ? qv + 1.f : __expf(qv);
        s += sq * zl[dk];
      }
      dnm[t] = s + 1e-5f;
    }
    // ---- a_mem numerator: sq @ Mem (two 64-row chunks staged into Ks) ----
    float pm[4][8] = {};
    const size_t mbase = ((size_t)seg * 32 + b * 8 + h) * 16384;
    for (int mc = 0; mc < 2; ++mc) {
      __syncthreads();
#pragma unroll
      for (int rep = 0; rep < 8; ++rep) {
        int lin = t + rep * 256;
        int row = lin >> 5, cc = lin & 31;
        *(float4*)&Ks[row][cc * 4] =
            *(const float4*)&Mem[mbase + (size_t)(mc * 64 + row) * 128 + cc * 4];
      }
      __syncthreads();
      for (int d2 = 0; d2 < 64; ++d2) {
        int dk = mc * 64 + d2;
        float sq[4];
#pragma unroll
        for (int i = 0; i < 4; ++i) {
          float qv = Qs[rq * 4 + i][dk];
          sq[i] = qv > 0.f ? qv + 1.f : __expf(qv);
        }
        float4 m0v = *(const float4*)&Ks[d2][dq * 8];
        float4 m1v = *(const float4*)&Ks[d2][dq * 8 + 4];
        float mm[8] = {m0v.x, m0v.y, m0v.z, m0v.w, m1v.x, m1v.y, m1v.z, m1v.w};
#pragma unroll
        for (int i = 0; i < 4; ++i)
#pragma unroll
          for (int j = 0; j < 8; ++j)
            pm[i][j] = fmaf(sq[i], mm[j], pm[i][j]);
      }
    }
    // ---- blend into head-mean accumulator ----
#pragma unroll
    for (int i = 0; i < 4; ++i) {
      float invl = 1.f / lrow[rq * 4 + i];
      float invd = 1.f / dnm[rq * 4 + i];
#pragma unroll
      for (int j = 0; j < 8; ++j)
        accum[i][j] += wmem * pm[i][j] * invd + wdot * o[i][j] * invl;
    }
  }
  // ---- write out: out[b, seg*512 + rb*64 + r, dv] ----
#pragma unroll
  for (int i = 0; i < 4; ++i) {
    size_t orow = segrow + rb * 64 + rq * 4 + i;
    float4 o0, o1;
    o0.x = accum[i][0]; o0.y = accum[i][1]; o0.z = accum[i][2]; o0.w = accum[i][3];
    o1.x = accum[i][4]; o1.y = accum[i][5]; o1.z = accum[i][6]; o1.w = accum[i][7];
    *(float4*)&Out[orow * 128 + dq * 8]     = o0;
    *(float4*)&Out[orow * 128 + dq * 8 + 4] = o1;
  }
}

// ---------------------------------------------------------------------------
extern "C" void kernel_launch(void* const* d_in, const int* in_sizes, int n_in,
                              void* d_out, int out_size, void* d_ws, size_t ws_size,
                              hipStream_t stream) {
  const float* x    = (const float*)d_in[0];
  const float* wq   = (const float*)d_in[1];
  const float* bq   = (const float*)d_in[2];
  const float* wk   = (const float*)d_in[3];
  const float* bk   = (const float*)d_in[4];
  const float* wv   = (const float*)d_in[5];
  const float* bv   = (const float*)d_in[6];
  const float* beta = (const float*)d_in[7];
  float* Out = (float*)d_out;

  // workspace layout (f32): Q | K | V | Mem(seg states) | Z  == ~437 MB
  float* Q   = (float*)d_ws;
  float* Kb  = Q  + (size_t)BS_ * 1024;
  float* Vb  = Kb + (size_t)BS_ * 1024;
  float* Mem = Vb + (size_t)BS_ * 1024;
  float* Zs  = Mem + (size_t)NSEG_ * 32 * 16384;

  dim3 g1(256, 8), b256(256);
  sgemm_bias<<<g1, b256, 0, stream>>>(x, wq, bq, Q);
  sgemm_bias<<<g1, b256, 0, stream>>>(x, wk, bk, Kb);
  sgemm_bias<<<g1, b256, 0, stream>>>(x, wv, bv, Vb);
  seg_kv<<<512, b256, 0, stream>>>(Kb, Vb, Mem, Zs);
  prefix_scan<<<512, b256, 0, stream>>>(Mem, Zs);
  attn_blend<<<dim3(8, 16, 4), b256, 0, stream>>>(Q, Kb, Vb, Mem, Zs, beta, Out);
}

// Round 3
// 3604.088 us; speedup vs baseline: 1.7335x; 1.7335x over previous
//
#include <hip/hip_runtime.h>
#include <hip/hip_bf16.h>

#define B_    4
#define S_    8192
#define D_    1024
#define H_    8
#define DKV_  128
#define SEG_  512
#define NSEG_ 16
#define BS_   (B_ * S_)   // 32768

typedef __attribute__((ext_vector_type(8))) short short8;
typedef __attribute__((ext_vector_type(4))) float f32x4;

__device__ inline void bf16split(float f, unsigned short& hi, unsigned short& lo) {
  __hip_bfloat16 h = __float2bfloat16(f);
  float hf = __bfloat162float(h);
  __hip_bfloat16 l = __float2bfloat16(f - hf);
  hi = *(unsigned short*)&h;
  lo = *(unsigned short*)&l;
}

// ---------------------------------------------------------------------------
// P0: W f32 [K=1024][N=1024] -> Wt_hi/Wt_lo bf16 [N][K] (transposed + split)
// ---------------------------------------------------------------------------
__global__ __launch_bounds__(256) void prep_w(
    const float* __restrict__ W, __hip_bfloat16* __restrict__ Whi,
    __hip_bfloat16* __restrict__ Wlo) {
  __shared__ float tile[32][33];
  const int k0 = blockIdx.x * 32, n0 = blockIdx.y * 32;
  const int tx = threadIdx.x & 31, ty = threadIdx.x >> 5;  // ty 0..7
#pragma unroll
  for (int r = 0; r < 4; ++r) {
    int k = ty + r * 8;
    tile[k][tx] = W[(size_t)(k0 + k) * 1024 + n0 + tx];
  }
  __syncthreads();
#pragma unroll
  for (int r = 0; r < 4; ++r) {
    int n = ty + r * 8;
    float v = tile[tx][n];
    unsigned short hb, lb;
    bf16split(v, hb, lb);
    *(unsigned short*)&Whi[(size_t)(n0 + n) * 1024 + k0 + tx] = hb;
    *(unsigned short*)&Wlo[(size_t)(n0 + n) * 1024 + k0 + tx] = lb;
  }
}

// ---------------------------------------------------------------------------
// K1: Y = A @ W + bias via MFMA bf16x3 (hi/lo split; err ~1e-5 vs f32).
// A f32 [32768][1024]; Wt_hi/lo bf16 [n][k]; Y f32 [32768][1024].
// 128x128 tile, BK=32, 256 thr = 4 waves (2x2 of 64x64), 16x16x32 MFMA.
// ---------------------------------------------------------------------------
__global__ __launch_bounds__(256) void gemm_bf16x3(
    const float* __restrict__ A, const __hip_bfloat16* __restrict__ Bhg,
    const __hip_bfloat16* __restrict__ Blg, const float* __restrict__ bias,
    float* __restrict__ Y) {
  __shared__ __hip_bfloat16 Ah[128][40];  // pad 40 -> frag reads 2-way (free)
  __shared__ __hip_bfloat16 Al[128][40];
  __shared__ __hip_bfloat16 Bh[128][40];
  __shared__ __hip_bfloat16 Bl[128][40];
  const int t = threadIdx.x;
  const int m0 = blockIdx.x * 128, n0 = blockIdx.y * 128;
  const int wave = t >> 6, lane = t & 63;
  const int wm = (wave >> 1) * 64, wn = (wave & 1) * 64;
  const int lr = lane & 15, ks = lane >> 4;   // frag row/col, k-octet

  f32x4 acc[4][4];
#pragma unroll
  for (int i = 0; i < 4; ++i)
#pragma unroll
    for (int j = 0; j < 4; ++j) acc[i][j] = (f32x4){0.f, 0.f, 0.f, 0.f};

  for (int k0 = 0; k0 < 1024; k0 += 32) {
    __syncthreads();
    // stage A (f32 -> hi/lo bf16): 128 rows x 32 k (1024 float4)
#pragma unroll
    for (int rep = 0; rep < 4; ++rep) {
      int lin = t + rep * 256;               // 0..1023
      int row = lin >> 3, kq = (lin & 7) * 4;
      float4 v = *(const float4*)&A[(size_t)(m0 + row) * 1024 + k0 + kq];
      ushort4 hv, lv;
      bf16split(v.x, hv.x, lv.x);
      bf16split(v.y, hv.y, lv.y);
      bf16split(v.z, hv.z, lv.z);
      bf16split(v.w, hv.w, lv.w);
      *(ushort4*)&Ah[row][kq] = hv;
      *(ushort4*)&Al[row][kq] = lv;
    }
    // stage B (bf16 [n][k]): 128 rows x 32 k = 512 uint4 per buffer
    // (FIX vs prior round: previous version loaded only half the tile)
#pragma unroll
    for (int rep = 0; rep < 2; ++rep) {
      int lin = t + rep * 256;               // 0..511
      int row = lin >> 2, kq = (lin & 3) * 8;
      *(uint4*)&Bh[row][kq] =
          *(const uint4*)&Bhg[(size_t)(n0 + row) * 1024 + k0 + kq];
      *(uint4*)&Bl[row][kq] =
          *(const uint4*)&Blg[(size_t)(n0 + row) * 1024 + k0 + kq];
    }
    __syncthreads();

    short8 afh[4], afl[4];
#pragma unroll
    for (int fm = 0; fm < 4; ++fm) {
      afh[fm] = *(short8*)&Ah[wm + fm * 16 + lr][ks * 8];
      afl[fm] = *(short8*)&Al[wm + fm * 16 + lr][ks * 8];
    }
#pragma unroll
    for (int fn = 0; fn < 4; ++fn) {
      short8 bfh = *(short8*)&Bh[wn + fn * 16 + lr][ks * 8];
      short8 bfl = *(short8*)&Bl[wn + fn * 16 + lr][ks * 8];
#pragma unroll
      for (int fm = 0; fm < 4; ++fm) {
        acc[fm][fn] = __builtin_amdgcn_mfma_f32_16x16x32_bf16(afh[fm], bfh, acc[fm][fn], 0, 0, 0);
        acc[fm][fn] = __builtin_amdgcn_mfma_f32_16x16x32_bf16(afh[fm], bfl, acc[fm][fn], 0, 0, 0);
        acc[fm][fn] = __builtin_amdgcn_mfma_f32_16x16x32_bf16(afl[fm], bfh, acc[fm][fn], 0, 0, 0);
      }
    }
  }
  // epilogue: D layout col=lane&15, row=(lane>>4)*4+reg  [m89-verified]
#pragma unroll
  for (int fn = 0; fn < 4; ++fn) {
    int n = n0 + wn + fn * 16 + lr;
    float bv = bias[n];
#pragma unroll
    for (int fm = 0; fm < 4; ++fm) {
      int mrow = m0 + wm + fm * 16 + ks * 4;
#pragma unroll
      for (int r = 0; r < 4; ++r)
        Y[(size_t)(mrow + r) * 1024 + n] = acc[fm][fn][r] + bv;
    }
  }
}

// ---------------------------------------------------------------------------
// K2: per-(seg,b,h) segment state (unchanged; passed in r1, small cost).
// ---------------------------------------------------------------------------
__global__ __launch_bounds__(256) void seg_kv(
    const float* __restrict__ Kb, const float* __restrict__ Vb,
    float* __restrict__ Mem, float* __restrict__ Zs) {
  __shared__ float sk[16][132];
  __shared__ float sv[16][132];
  const int bx  = blockIdx.x;
  const int seg = bx >> 5;
  const int bh  = bx & 31;
  const int b   = bh >> 3, h = bh & 7;
  const int t   = threadIdx.x;
  const int tr  = t >> 4, tc = t & 15;
  float acc[8][8] = {};
  float zacc = 0.f;
  const size_t rowbase = (size_t)b * S_ + (size_t)seg * SEG_;
  for (int l0 = 0; l0 < SEG_; l0 += 16) {
    __syncthreads();
#pragma unroll
    for (int rep = 0; rep < 2; ++rep) {
      int lin = t + rep * 256;
      int row = lin >> 5;
      int dqc = lin & 31;
      size_t g = (rowbase + l0 + row) * 1024 + h * 128 + dqc * 4;
      float4 kv = *(const float4*)&Kb[g];
      float4 vv = *(const float4*)&Vb[g];
      sk[row][dqc * 4 + 0] = kv.x > 0.f ? kv.x + 1.f : __expf(kv.x);
      sk[row][dqc * 4 + 1] = kv.y > 0.f ? kv.y + 1.f : __expf(kv.y);
      sk[row][dqc * 4 + 2] = kv.z > 0.f ? kv.z + 1.f : __expf(kv.z);
      sk[row][dqc * 4 + 3] = kv.w > 0.f ? kv.w + 1.f : __expf(kv.w);
      *(float4*)&sv[row][dqc * 4] = vv;
    }
    __syncthreads();
#pragma unroll
    for (int l = 0; l < 16; ++l) {
      float a[8], v[8];
      *(float4*)&a[0] = *(const float4*)&sk[l][tr * 8];
      *(float4*)&a[4] = *(const float4*)&sk[l][tr * 8 + 4];
      *(float4*)&v[0] = *(const float4*)&sv[l][tc * 8];
      *(float4*)&v[4] = *(const float4*)&sv[l][tc * 8 + 4];
#pragma unroll
      for (int i = 0; i < 8; ++i)
#pragma unroll
        for (int j = 0; j < 8; ++j)
          acc[i][j] = fmaf(a[i], v[j], acc[i][j]);
    }
    if (t < 128) {
#pragma unroll
      for (int l = 0; l < 16; ++l) zacc += sk[l][t];
    }
  }
  const size_t base = ((size_t)seg * 32 + bh) * 16384;
#pragma unroll
  for (int i = 0; i < 8; ++i)
#pragma unroll
    for (int j = 0; j < 8; j += 4) {
      float4 o;
      o.x = acc[i][j + 0]; o.y = acc[i][j + 1];
      o.z = acc[i][j + 2]; o.w = acc[i][j + 3];
      *(float4*)&Mem[base + (size_t)(tr * 8 + i) * 128 + tc * 8 + j] = o;
    }
  if (t < 128) Zs[((size_t)seg * 32 + bh) * 128 + t] = zacc * (float)SEG_;
}

// ---------------------------------------------------------------------------
// K3: inclusive prefix over segments (unchanged).
// ---------------------------------------------------------------------------
__global__ __launch_bounds__(256) void prefix_scan(
    float* __restrict__ Mem, float* __restrict__ Zs) {
  const int bx = blockIdx.x;
  const int bh = bx & 31;
  const int part = bx >> 5;
  const int t = threadIdx.x;
  for (int jj = 0; jj < 4; ++jj) {
    size_t flat = ((size_t)part * 4 + jj) * 256 + t;
    float run = 0.f;
#pragma unroll
    for (int seg = 0; seg < NSEG_; ++seg) {
      size_t idx = ((size_t)seg * 32 + bh) * 16384 + flat;
      run += Mem[idx];
      Mem[idx] = run;
    }
  }
  if (part == 0 && t < 128) {
    float run = 0.f;
#pragma unroll
    for (int seg = 0; seg < NSEG_; ++seg) {
      size_t idx = ((size_t)seg * 32 + bh) * 128 + t;
      run += Zs[idx];
      Zs[idx] = run;
    }
  }
}

// ---------------------------------------------------------------------------
// K4 v2: flash attention + retrieval, register softmax, 75.5KB LDS (2 blk/CU).
// Thread (rq=t>>4, dq=t&15): rows rq*4+i; score cols dq+16j (2-way LDS);
// dv cols {dq*4..+3} u {64+dq*4..+3} (2-way LDS).
// ---------------------------------------------------------------------------
__global__ __launch_bounds__(256) void attn_blend(
    const float* __restrict__ Qb, const float* __restrict__ Kb,
    const float* __restrict__ Vb, const float* __restrict__ Mem,
    const float* __restrict__ Zs, const float* __restrict__ beta,
    float* __restrict__ Out) {
  __shared__ float Qs[64][132];
  __shared__ float Ks[32][132];   // K chunk; reused for Mem chunks
  __shared__ float Vs[32][132];
  __shared__ float Ss[64][36];    // p block (64 x 32), 2-way banks
  __shared__ float zl[128];

  const int t   = threadIdx.x;
  const int rb  = blockIdx.x;    // 0..7
  const int seg = blockIdx.y;    // 0..15
  const int b   = blockIdx.z;    // 0..3
  const int rq  = t >> 4;        // 0..15
  const int dq  = t & 15;        // 0..15
  const float scale = 0.08838834764831845f;  // 1/sqrt(128)
  const float bsig  = 1.f / (1.f + __expf(-beta[0]));
  const float wmem  = bsig * 0.125f;
  const float wdot  = (1.f - bsig) * 0.125f;

  float accum[4][8] = {};
  const size_t segrow = (size_t)b * S_ + (size_t)seg * SEG_;

  for (int h = 0; h < H_; ++h) {
    __syncthreads();   // protect Qs/zl from previous head's readers
#pragma unroll
    for (int rep = 0; rep < 8; ++rep) {
      int lin = t + rep * 256;
      int row = lin >> 5, c = (lin & 31) * 4;
      *(float4*)&Qs[row][c] =
          *(const float4*)&Qb[(segrow + rb * 64 + row) * 1024 + h * 128 + c];
    }
    if (t < 128) zl[t] = Zs[((size_t)seg * 32 + b * 8 + h) * 128 + t];
    __syncthreads();

    float o[4][8] = {};
    float mreg[4] = {-1e30f, -1e30f, -1e30f, -1e30f};
    float lreg[4] = {0.f, 0.f, 0.f, 0.f};

    // ---- local softmax attention over 16 key chunks of 32 ----
    for (int c = 0; c < 16; ++c) {
#pragma unroll
      for (int rep = 0; rep < 4; ++rep) {
        int lin = t + rep * 256;       // 0..1023 float4s
        int row = lin >> 5, cc = (lin & 31) * 4;
        size_t g = (segrow + c * 32 + row) * 1024 + h * 128 + cc;
        *(float4*)&Ks[row][cc] = *(const float4*)&Kb[g];
        *(float4*)&Vs[row][cc] = *(const float4*)&Vb[g];
      }
      __syncthreads();
      // scores: 4 rows x 2 cols (dq, dq+16)
      float sacc[4][2] = {{0.f,0.f},{0.f,0.f},{0.f,0.f},{0.f,0.f}};
#pragma unroll 4
      for (int d = 0; d < 128; d += 4) {
        float4 ka = *(const float4*)&Ks[dq][d];
        float4 kc = *(const float4*)&Ks[dq + 16][d];
#pragma unroll
        for (int i = 0; i < 4; ++i) {
          float4 qv = *(const float4*)&Qs[rq * 4 + i][d];
          sacc[i][0] = fmaf(qv.x, ka.x, sacc[i][0]);
          sacc[i][0] = fmaf(qv.y, ka.y, sacc[i][0]);
          sacc[i][0] = fmaf(qv.z, ka.z, sacc[i][0]);
          sacc[i][0] = fmaf(qv.w, ka.w, sacc[i][0]);
          sacc[i][1] = fmaf(qv.x, kc.x, sacc[i][1]);
          sacc[i][1] = fmaf(qv.y, kc.y, sacc[i][1]);
          sacc[i][1] = fmaf(qv.z, kc.z, sacc[i][1]);
          sacc[i][1] = fmaf(qv.w, kc.w, sacc[i][1]);
        }
      }
      // register online softmax: reduce over dq nibble (lane bits 0..3)
#pragma unroll
      for (int i = 0; i < 4; ++i) {
        float s0 = sacc[i][0] * scale, s1 = sacc[i][1] * scale;
        float pmax = fmaxf(s0, s1);
        pmax = fmaxf(pmax, __shfl_xor(pmax, 1));
        pmax = fmaxf(pmax, __shfl_xor(pmax, 2));
        pmax = fmaxf(pmax, __shfl_xor(pmax, 4));
        pmax = fmaxf(pmax, __shfl_xor(pmax, 8));
        float mnew = fmaxf(mreg[i], pmax);
        float f = __expf(mreg[i] - mnew);
        float p0 = __expf(s0 - mnew);
        float p1 = __expf(s1 - mnew);
        float ps = p0 + p1;
        ps += __shfl_xor(ps, 1);
        ps += __shfl_xor(ps, 2);
        ps += __shfl_xor(ps, 4);
        ps += __shfl_xor(ps, 8);
        lreg[i] = lreg[i] * f + ps;
        mreg[i] = mnew;
        Ss[rq * 4 + i][dq] = p0;
        Ss[rq * 4 + i][dq + 16] = p1;
#pragma unroll
        for (int j = 0; j < 8; ++j) o[i][j] *= f;
      }
      __syncthreads();
      // PV: o[i][0..3] -> dv dq*4+j ; o[i][4..7] -> dv 64+dq*4+(j-4)
#pragma unroll
      for (int mg = 0; mg < 8; ++mg) {
        float4 ps4[4], vlo[4], vhi[4];
#pragma unroll
        for (int i = 0; i < 4; ++i)
          ps4[i] = *(const float4*)&Ss[rq * 4 + i][mg * 4];
#pragma unroll
        for (int u = 0; u < 4; ++u) {
          vlo[u] = *(const float4*)&Vs[mg * 4 + u][dq * 4];
          vhi[u] = *(const float4*)&Vs[mg * 4 + u][64 + dq * 4];
        }
#pragma unroll
        for (int i = 0; i < 4; ++i) {
          float pv[4] = {ps4[i].x, ps4[i].y, ps4[i].z, ps4[i].w};
#pragma unroll
          for (int u = 0; u < 4; ++u) {
            o[i][0] = fmaf(pv[u], vlo[u].x, o[i][0]);
            o[i][1] = fmaf(pv[u], vlo[u].y, o[i][1]);
            o[i][2] = fmaf(pv[u], vlo[u].z, o[i][2]);
            o[i][3] = fmaf(pv[u], vlo[u].w, o[i][3]);
            o[i][4] = fmaf(pv[u], vhi[u].x, o[i][4]);
            o[i][5] = fmaf(pv[u], vhi[u].y, o[i][5]);
            o[i][6] = fmaf(pv[u], vhi[u].z, o[i][6]);
            o[i][7] = fmaf(pv[u], vhi[u].w, o[i][7]);
          }
        }
      }
      __syncthreads();
    }

    // ---- transform Qs in place: sq = elu(q)+1 ----
#pragma unroll
    for (int rep = 0; rep < 8; ++rep) {
      int lin = t + rep * 256;
      int row = lin >> 5, c = (lin & 31) * 4;
      float4 qv = *(const float4*)&Qs[row][c];
      qv.x = qv.x > 0.f ? qv.x + 1.f : __expf(qv.x);
      qv.y = qv.y > 0.f ? qv.y + 1.f : __expf(qv.y);
      qv.z = qv.z > 0.f ? qv.z + 1.f : __expf(qv.z);
      qv.w = qv.w > 0.f ? qv.w + 1.f : __expf(qv.w);
      *(float4*)&Qs[row][c] = qv;
    }
    __syncthreads();

    // ---- denominator: (sq . z) per row, register reduce ----
    float dreg[4];
    {
      float4 z0 = *(const float4*)&zl[dq * 8];
      float4 z1 = *(const float4*)&zl[dq * 8 + 4];
#pragma unroll
      for (int i = 0; i < 4; ++i) {
        float4 a0 = *(const float4*)&Qs[rq * 4 + i][dq * 8];
        float4 a1 = *(const float4*)&Qs[rq * 4 + i][dq * 8 + 4];
        float s = a0.x * z0.x + a0.y * z0.y + a0.z * z0.z + a0.w * z0.w +
                  a1.x * z1.x + a1.y * z1.y + a1.z * z1.z + a1.w * z1.w;
        s += __shfl_xor(s, 1);
        s += __shfl_xor(s, 2);
        s += __shfl_xor(s, 4);
        s += __shfl_xor(s, 8);
        dreg[i] = s + 1e-5f;
      }
    }

    // ---- a_mem numerator: sq @ Mem, 4 chunks of 32 dk staged into Ks ----
    float pm[4][8] = {};
    const size_t mbase = ((size_t)seg * 32 + b * 8 + h) * 16384;
    for (int mc = 0; mc < 4; ++mc) {
      __syncthreads();
#pragma unroll
      for (int rep = 0; rep < 4; ++rep) {
        int lin = t + rep * 256;
        int row = lin >> 5, cc = (lin & 31) * 4;
        *(float4*)&Ks[row][cc] =
            *(const float4*)&Mem[mbase + (size_t)(mc * 32 + row) * 128 + cc];
      }
      __syncthreads();
#pragma unroll
      for (int dg = 0; dg < 8; ++dg) {
        float4 sq4[4], mlo[4], mhi[4];
#pragma unroll
        for (int i = 0; i < 4; ++i)
          sq4[i] = *(const float4*)&Qs[rq * 4 + i][mc * 32 + dg * 4];
#pragma unroll
        for (int u = 0; u < 4; ++u) {
          mlo[u] = *(const float4*)&Ks[dg * 4 + u][dq * 4];
          mhi[u] = *(const float4*)&Ks[dg * 4 + u][64 + dq * 4];
        }
#pragma unroll
        for (int i = 0; i < 4; ++i) {
          float sq[4] = {sq4[i].x, sq4[i].y, sq4[i].z, sq4[i].w};
#pragma unroll
          for (int u = 0; u < 4; ++u) {
            pm[i][0] = fmaf(sq[u], mlo[u].x, pm[i][0]);
            pm[i][1] = fmaf(sq[u], mlo[u].y, pm[i][1]);
            pm[i][2] = fmaf(sq[u], mlo[u].z, pm[i][2]);
            pm[i][3] = fmaf(sq[u], mlo[u].w, pm[i][3]);
            pm[i][4] = fmaf(sq[u], mhi[u].x, pm[i][4]);
            pm[i][5] = fmaf(sq[u], mhi[u].y, pm[i][5]);
            pm[i][6] = fmaf(sq[u], mhi[u].z, pm[i][6]);
            pm[i][7] = fmaf(sq[u], mhi[u].w, pm[i][7]);
          }
        }
      }
    }

    // ---- blend ----
#pragma unroll
    for (int i = 0; i < 4; ++i) {
      float cd = wmem / dreg[i];
      float cl = wdot / lreg[i];
#pragma unroll
      for (int j = 0; j < 8; ++j)
        accum[i][j] += cd * pm[i][j] + cl * o[i][j];
    }
  }

  // ---- write out ----
#pragma unroll
  for (int i = 0; i < 4; ++i) {
    size_t orow = segrow + rb * 64 + rq * 4 + i;
    float4 o0, o1;
    o0.x = accum[i][0]; o0.y = accum[i][1]; o0.z = accum[i][2]; o0.w = accum[i][3];
    o1.x = accum[i][4]; o1.y = accum[i][5]; o1.z = accum[i][6]; o1.w = accum[i][7];
    *(float4*)&Out[orow * 128 + dq * 4] = o0;
    *(float4*)&Out[orow * 128 + 64 + dq * 4] = o1;
  }
}

// ---------------------------------------------------------------------------
extern "C" void kernel_launch(void* const* d_in, const int* in_sizes, int n_in,
                              void* d_out, int out_size, void* d_ws, size_t ws_size,
                              hipStream_t stream) {
  const float* x    = (const float*)d_in[0];
  const float* wq   = (const float*)d_in[1];
  const float* bq   = (const float*)d_in[2];
  const float* wk   = (const float*)d_in[3];
  const float* bk   = (const float*)d_in[4];
  const float* wv   = (const float*)d_in[5];
  const float* bv   = (const float*)d_in[6];
  const float* beta = (const float*)d_in[7];
  float* Out = (float*)d_out;

  // ws layout (f32 unless noted): Q | K | V | Mem | Zs | 6x bf16 Wt  ~429 MB
  float* Q   = (float*)d_ws;
  float* Kb  = Q  + (size_t)BS_ * 1024;
  float* Vb  = Kb + (size_t)BS_ * 1024;
  float* Mem = Vb + (size_t)BS_ * 1024;
  float* Zs  = Mem + (size_t)NSEG_ * 32 * 16384;
  __hip_bfloat16* Wt = (__hip_bfloat16*)(Zs + (size_t)NSEG_ * 32 * 128);
  const size_t WSZ = (size_t)1024 * 1024;
  __hip_bfloat16* Wqh = Wt;
  __hip_bfloat16* Wql = Wqh + WSZ;
  __hip_bfloat16* Wkh = Wql + WSZ;
  __hip_bfloat16* Wkl = Wkh + WSZ;
  __hip_bfloat16* Wvh = Wkl + WSZ;
  __hip_bfloat16* Wvl = Wvh + WSZ;

  dim3 b256(256);
  dim3 gp(32, 32);
  prep_w<<<gp, b256, 0, stream>>>(wq, Wqh, Wql);
  prep_w<<<gp, b256, 0, stream>>>(wk, Wkh, Wkl);
  prep_w<<<gp, b256, 0, stream>>>(wv, Wvh, Wvl);

  dim3 gg(256, 8);
  gemm_bf16x3<<<gg, b256, 0, stream>>>(x, Wqh, Wql, bq, Q);
  gemm_bf16x3<<<gg, b256, 0, stream>>>(x, Wkh, Wkl, bk, Kb);
  gemm_bf16x3<<<gg, b256, 0, stream>>>(x, Wvh, Wvl, bv, Vb);

  seg_kv<<<512, b256, 0, stream>>>(Kb, Vb, Mem, Zs);
  prefix_scan<<<512, b256, 0, stream>>>(Mem, Zs);
  attn_blend<<<dim3(8, 16, 4), b256, 0, stream>>>(Q, Kb, Vb, Mem, Zs, beta, Out);
}

// Round 5
// 1728.746 us; speedup vs baseline: 3.6140x; 2.0848x over previous
//
#include <hip/hip_runtime.h>
#include <hip/hip_bf16.h>

#define B_    4
#define S_    8192
#define D_    1024
#define H_    8
#define DKV_  128
#define SEG_  512
#define NSEG_ 16
#define BS_   (B_ * S_)   // 32768

typedef __attribute__((ext_vector_type(8))) short short8;
typedef __attribute__((ext_vector_type(4))) float f32x4;

__device__ inline float bf2f(unsigned short u) {
  unsigned int x = ((unsigned int)u) << 16;
  return __uint_as_float(x);
}
__device__ inline unsigned short f2bf(float f) {
  __hip_bfloat16 h = __float2bfloat16(f);
  return *(unsigned short*)&h;
}
__device__ inline void bf16split(float f, unsigned short& hi, unsigned short& lo) {
  __hip_bfloat16 h = __float2bfloat16(f);
  float hf = __bfloat162float(h);
  __hip_bfloat16 l = __float2bfloat16(f - hf);
  hi = *(unsigned short*)&h;
  lo = *(unsigned short*)&l;
}

// ---------------------------------------------------------------------------
// P0: W f32 [K][N] -> Wt_hi/Wt_lo bf16 [N][K] (transposed + split)
// ---------------------------------------------------------------------------
__global__ __launch_bounds__(256) void prep_w(
    const float* __restrict__ W, __hip_bfloat16* __restrict__ Whi,
    __hip_bfloat16* __restrict__ Wlo) {
  __shared__ float tile[32][33];
  const int k0 = blockIdx.x * 32, n0 = blockIdx.y * 32;
  const int tx = threadIdx.x & 31, ty = threadIdx.x >> 5;
#pragma unroll
  for (int r = 0; r < 4; ++r) {
    int k = ty + r * 8;
    tile[k][tx] = W[(size_t)(k0 + k) * 1024 + n0 + tx];
  }
  __syncthreads();
#pragma unroll
  for (int r = 0; r < 4; ++r) {
    int n = ty + r * 8;
    float v = tile[tx][n];
    unsigned short hb, lb;
    bf16split(v, hb, lb);
    *(unsigned short*)&Whi[(size_t)(n0 + n) * 1024 + k0 + tx] = hb;
    *(unsigned short*)&Wlo[(size_t)(n0 + n) * 1024 + k0 + tx] = lb;
  }
}

// ---------------------------------------------------------------------------
// K1: Y = A @ W + bias via MFMA bf16x3.
// MODE 0: write hi/lo bf16 planes [m][1024] (Q, K).
// MODE 1: write single-bf16 transposed plane VT[((b*8+h)*128+dv)*8192 + s].
// ---------------------------------------------------------------------------
template <int MODE>
__global__ __launch_bounds__(256) void gemm_bf16x3(
    const float* __restrict__ A, const __hip_bfloat16* __restrict__ Bhg,
    const __hip_bfloat16* __restrict__ Blg, const float* __restrict__ bias,
    __hip_bfloat16* __restrict__ Oh, __hip_bfloat16* __restrict__ Ol) {
  __shared__ __hip_bfloat16 Ah[128][40];
  __shared__ __hip_bfloat16 Al[128][40];
  __shared__ __hip_bfloat16 Bh[128][40];
  __shared__ __hip_bfloat16 Bl[128][40];
  const int t = threadIdx.x;
  const int m0 = blockIdx.x * 128, n0 = blockIdx.y * 128;
  const int wave = t >> 6, lane = t & 63;
  const int wm = (wave >> 1) * 64, wn = (wave & 1) * 64;
  const int lr = lane & 15, ks = lane >> 4;

  f32x4 acc[4][4];
#pragma unroll
  for (int i = 0; i < 4; ++i)
#pragma unroll
    for (int j = 0; j < 4; ++j) acc[i][j] = (f32x4){0.f, 0.f, 0.f, 0.f};

  for (int k0 = 0; k0 < 1024; k0 += 32) {
    __syncthreads();
#pragma unroll
    for (int rep = 0; rep < 4; ++rep) {
      int lin = t + rep * 256;
      int row = lin >> 3, kq = (lin & 7) * 4;
      float4 v = *(const float4*)&A[(size_t)(m0 + row) * 1024 + k0 + kq];
      ushort4 hv, lv;
      bf16split(v.x, hv.x, lv.x);
      bf16split(v.y, hv.y, lv.y);
      bf16split(v.z, hv.z, lv.z);
      bf16split(v.w, hv.w, lv.w);
      *(ushort4*)&Ah[row][kq] = hv;
      *(ushort4*)&Al[row][kq] = lv;
    }
#pragma unroll
    for (int rep = 0; rep < 2; ++rep) {
      int lin = t + rep * 256;
      int row = lin >> 2, kq = (lin & 3) * 8;
      *(uint4*)&Bh[row][kq] =
          *(const uint4*)&Bhg[(size_t)(n0 + row) * 1024 + k0 + kq];
      *(uint4*)&Bl[row][kq] =
          *(const uint4*)&Blg[(size_t)(n0 + row) * 1024 + k0 + kq];
    }
    __syncthreads();

    short8 afh[4], afl[4];
#pragma unroll
    for (int fm = 0; fm < 4; ++fm) {
      afh[fm] = *(short8*)&Ah[wm + fm * 16 + lr][ks * 8];
      afl[fm] = *(short8*)&Al[wm + fm * 16 + lr][ks * 8];
    }
#pragma unroll
    for (int fn = 0; fn < 4; ++fn) {
      short8 bfh = *(short8*)&Bh[wn + fn * 16 + lr][ks * 8];
      short8 bfl = *(short8*)&Bl[wn + fn * 16 + lr][ks * 8];
#pragma unroll
      for (int fm = 0; fm < 4; ++fm) {
        acc[fm][fn] = __builtin_amdgcn_mfma_f32_16x16x32_bf16(afh[fm], bfh, acc[fm][fn], 0, 0, 0);
        acc[fm][fn] = __builtin_amdgcn_mfma_f32_16x16x32_bf16(afh[fm], bfl, acc[fm][fn], 0, 0, 0);
        acc[fm][fn] = __builtin_amdgcn_mfma_f32_16x16x32_bf16(afl[fm], bfh, acc[fm][fn], 0, 0, 0);
      }
    }
  }
  // epilogue: C layout col=lane&15, row=(lane>>4)*4+reg  [HW-verified]
#pragma unroll
  for (int fn = 0; fn < 4; ++fn) {
    int n = n0 + wn + fn * 16 + lr;
    float bv = bias[n];
#pragma unroll
    for (int fm = 0; fm < 4; ++fm) {
      int mrow = m0 + wm + fm * 16 + ks * 4;
      if (MODE == 0) {
#pragma unroll
        for (int r = 0; r < 4; ++r) {
          float val = acc[fm][fn][r] + bv;
          unsigned short hb, lb;
          bf16split(val, hb, lb);
          *(unsigned short*)&Oh[(size_t)(mrow + r) * 1024 + n] = hb;
          *(unsigned short*)&Ol[(size_t)(mrow + r) * 1024 + n] = lb;
        }
      } else {
        int bb = mrow >> 13, s = mrow & 8191;
        size_t vtix = (((size_t)(bb * 8 + (n >> 7))) * 128 + (n & 127)) * 8192 + s;
        ushort4 pk;
        pk.x = f2bf(acc[fm][fn][0] + bv);
        pk.y = f2bf(acc[fm][fn][1] + bv);
        pk.z = f2bf(acc[fm][fn][2] + bv);
        pk.w = f2bf(acc[fm][fn][3] + bv);
        *(ushort4*)&Oh[vtix] = pk;
      }
    }
  }
}

// ---------------------------------------------------------------------------
// K2: per-(seg,b,h) state: SkvT[dv][dk] = sum_l v[l][dv]*sk[l][dk] (f32),
//     Zs[dk] = (sum_l sk[l][dk]) * SEG.  sk=elu(k)+1, k = Kh+Kl, v from VT.
// ---------------------------------------------------------------------------
__global__ __launch_bounds__(256) void seg_kv(
    const __hip_bfloat16* __restrict__ Khp, const __hip_bfloat16* __restrict__ Klp,
    const __hip_bfloat16* __restrict__ VTp, float* __restrict__ MemST,
    float* __restrict__ Zs) {
  __shared__ float sk[16][132];
  __shared__ float svT[128][18];
  const int bx = blockIdx.x;
  const int seg = bx >> 5, bh = bx & 31;
  const int b = bh >> 3, h = bh & 7;
  const int t = threadIdx.x;
  const int tr = t >> 4, tc = t & 15;    // dv0 = tr*8, dk0 = tc*8
  float acc[8][8] = {};
  float zacc = 0.f;
  const size_t rowbase = (size_t)b * S_ + (size_t)seg * SEG_;
  const size_t sbase = (size_t)seg * SEG_;
  const size_t vtbase = (size_t)(b * 8 + h) * 128 * 8192;
  for (int l0 = 0; l0 < SEG_; l0 += 16) {
    __syncthreads();
    {
      int row = t >> 4, oct = t & 15;
      size_t g = (rowbase + l0 + row) * 1024 + h * 128 + oct * 8;
      short8 hv = *(const short8*)&Khp[g];
      short8 lv = *(const short8*)&Klp[g];
#pragma unroll
      for (int e = 0; e < 8; ++e) {
        float kvf = bf2f((unsigned short)hv[e]) + bf2f((unsigned short)lv[e]);
        sk[row][oct * 8 + e] = kvf > 0.f ? kvf + 1.f : __expf(kvf);
      }
      int dv = t >> 1, half = t & 1;
      short8 vv = *(const short8*)&VTp[vtbase + (size_t)dv * 8192 + sbase + l0 + half * 8];
#pragma unroll
      for (int e = 0; e < 8; ++e) svT[dv][half * 8 + e] = bf2f((unsigned short)vv[e]);
    }
    __syncthreads();
#pragma unroll
    for (int l = 0; l < 16; ++l) {
      float a[8], kk[8];
#pragma unroll
      for (int i = 0; i < 8; ++i) a[i] = svT[tr * 8 + i][l];
      *(float4*)&kk[0] = *(const float4*)&sk[l][tc * 8];
      *(float4*)&kk[4] = *(const float4*)&sk[l][tc * 8 + 4];
#pragma unroll
      for (int i = 0; i < 8; ++i)
#pragma unroll
        for (int j = 0; j < 8; ++j)
          acc[i][j] = fmaf(a[i], kk[j], acc[i][j]);
    }
    if (t < 128) {
#pragma unroll
      for (int l = 0; l < 16; ++l) zacc += sk[l][t];
    }
  }
  const size_t base = ((size_t)seg * 32 + bh) * 16384;
#pragma unroll
  for (int i = 0; i < 8; ++i)
#pragma unroll
    for (int j = 0; j < 8; j += 4) {
      float4 o = {acc[i][j], acc[i][j + 1], acc[i][j + 2], acc[i][j + 3]};
      *(float4*)&MemST[base + (size_t)(tr * 8 + i) * 128 + tc * 8 + j] = o;
    }
  if (t < 128) Zs[((size_t)seg * 32 + bh) * 128 + t] = zacc * (float)SEG_;
}

// ---------------------------------------------------------------------------
// K3: inclusive prefix over segments; also emits bf16 MemT plane.
// ---------------------------------------------------------------------------
__global__ __launch_bounds__(256) void prefix_scan(
    float* __restrict__ Mem, __hip_bfloat16* __restrict__ MT,
    float* __restrict__ Zs) {
  const int bx = blockIdx.x;
  const int bh = bx & 31;
  const int part = bx >> 5;
  const int t = threadIdx.x;
  for (int jj = 0; jj < 4; ++jj) {
    size_t flat = ((size_t)part * 4 + jj) * 256 + t;
    float run = 0.f;
#pragma unroll
    for (int seg = 0; seg < NSEG_; ++seg) {
      size_t idx = ((size_t)seg * 32 + bh) * 16384 + flat;
      run += Mem[idx];
      Mem[idx] = run;
      *(unsigned short*)&MT[idx] = f2bf(run);
    }
  }
  if (part == 0 && t < 128) {
    float run = 0.f;
#pragma unroll
    for (int seg = 0; seg < NSEG_; ++seg) {
      size_t idx = ((size_t)seg * 32 + bh) * 128 + t;
      run += Zs[idx];
      Zs[idx] = run;
    }
  }
}

// ---------------------------------------------------------------------------
// K4 v3b: MFMA flash attention + retrieval. Block = (rb, seg, b), 4 waves,
// wave owns 16 q-rows. FIX vs v3: K-chunk staging now covers all 128 dk
// (was rep<2 / oct&7 -> only dk 0..63 staged -> NaN from garbage LDS).
// LDS 61.5 KB -> 2 blocks/CU.
// ---------------------------------------------------------------------------
__global__ __launch_bounds__(256, 2) void attn_blend_mfma(
    const __hip_bfloat16* __restrict__ Qhp, const __hip_bfloat16* __restrict__ Qlp,
    const __hip_bfloat16* __restrict__ Khp, const __hip_bfloat16* __restrict__ Klp,
    const __hip_bfloat16* __restrict__ VTp, const __hip_bfloat16* __restrict__ MT,
    const float* __restrict__ Zs, const float* __restrict__ beta,
    float* __restrict__ Out) {
  __shared__ __hip_bfloat16 KhS[64][136];
  __shared__ __hip_bfloat16 KlS[64][136];
  __shared__ __hip_bfloat16 VtS[128][72];   // V^T chunk / MemT chunk
  __shared__ __hip_bfloat16 Ps[64][72];     // P (per-wave 16-row slabs)
  __shared__ float zl[128];

  const int t = threadIdx.x;
  const int rb = blockIdx.x, seg = blockIdx.y, b = blockIdx.z;
  const int wave = t >> 6, lane = t & 63;
  const int lr = lane & 15, lg = lane >> 4;
  const float scale = 0.08838834764831845f;  // 1/sqrt(128)
  const float bsig = 1.f / (1.f + __expf(-beta[0]));
  const float wmem = bsig * 0.125f, wdot = (1.f - bsig) * 0.125f;

  const size_t segrow = (size_t)b * S_ + (size_t)seg * SEG_;
  const int qrow = rb * 64 + wave * 16 + lr;          // A-fragment row
  const size_t qbase = (segrow + qrow) * 1024;

  f32x4 accum[8];
#pragma unroll
  for (int v = 0; v < 8; ++v) accum[v] = (f32x4){0.f, 0.f, 0.f, 0.f};

  for (int h = 0; h < H_; ++h) {
    const int bh = b * 8 + h;
    __syncthreads();                         // prev head fully done
    if (t < 128) zl[t] = Zs[((size_t)seg * 32 + bh) * 128 + t];

    // ---- Q fragments (hi/lo) ----
    short8 ah[4], al[4];
#pragma unroll
    for (int ksv = 0; ksv < 4; ++ksv) {
      size_t off = qbase + h * 128 + lg * 8 + ksv * 32;
      ah[ksv] = *(const short8*)&Qhp[off];
      al[ksv] = *(const short8*)&Qlp[off];
    }

    // ---- sq = elu(q)+1: bf16 frags + f32 stash ----
    short8 sqf[4];
    f32x4 sqa[4], sqb[4];
#pragma unroll
    for (int ksv = 0; ksv < 4; ++ksv) {
#pragma unroll
      for (int e = 0; e < 8; ++e) {
        float q = bf2f((unsigned short)ah[ksv][e]) + bf2f((unsigned short)al[ksv][e]);
        float s = q > 0.f ? q + 1.f : __expf(q);
        if (e < 4) sqa[ksv][e] = s; else sqb[ksv][e - 4] = s;
        sqf[ksv][e] = (short)f2bf(s);
      }
    }
    __syncthreads();                         // zl visible

    // ---- denominator: (sq . z) for row lr ----
    float dnm;
    {
      float part = 0.f;
#pragma unroll
      for (int ksv = 0; ksv < 4; ++ksv) {
        float4 z0 = *(const float4*)&zl[lg * 8 + ksv * 32];
        float4 z1 = *(const float4*)&zl[lg * 8 + ksv * 32 + 4];
        part += sqa[ksv][0] * z0.x + sqa[ksv][1] * z0.y + sqa[ksv][2] * z0.z +
                sqa[ksv][3] * z0.w + sqb[ksv][0] * z1.x + sqb[ksv][1] * z1.y +
                sqb[ksv][2] * z1.z + sqb[ksv][3] * z1.w;
      }
      part += __shfl_xor(part, 16);
      part += __shfl_xor(part, 32);
      dnm = part + 1e-5f;
    }

    // ---- retrieval: pm = sq @ MemT ----
    f32x4 pm[8];
#pragma unroll
    for (int v = 0; v < 8; ++v) pm[v] = (f32x4){0.f, 0.f, 0.f, 0.f};
    const size_t mtbase = ((size_t)seg * 32 + bh) * 16384;
#pragma unroll 1
    for (int mc = 0; mc < 2; ++mc) {
      if (mc) __syncthreads();
#pragma unroll
      for (int rep = 0; rep < 4; ++rep) {
        int lin = t + rep * 256;
        int dv = lin >> 3, oct = lin & 7;
        *(short8*)&VtS[dv][oct * 8] =
            *(const short8*)&MT[mtbase + (size_t)dv * 128 + mc * 64 + oct * 8];
      }
      __syncthreads();
#pragma unroll
      for (int ks2 = 0; ks2 < 2; ++ks2) {
        short8 af = sqf[mc * 2 + ks2];
#pragma unroll
        for (int vb = 0; vb < 8; ++vb) {
          short8 bf = *(const short8*)&VtS[vb * 16 + lr][ks2 * 32 + lg * 8];
          pm[vb] = __builtin_amdgcn_mfma_f32_16x16x32_bf16(af, bf, pm[vb], 0, 0, 0);
        }
      }
    }
    {
      float cdr[4];
#pragma unroll
      for (int r = 0; r < 4; ++r) cdr[r] = wmem / __shfl(dnm, lg * 4 + r);
#pragma unroll
      for (int vb = 0; vb < 8; ++vb) {
        accum[vb][0] += cdr[0] * pm[vb][0];
        accum[vb][1] += cdr[1] * pm[vb][1];
        accum[vb][2] += cdr[2] * pm[vb][2];
        accum[vb][3] += cdr[3] * pm[vb][3];
      }
    }

    // ---- local softmax attention over 8 chunks of 64 keys ----
    f32x4 o[8];
#pragma unroll
    for (int v = 0; v < 8; ++v) o[v] = (f32x4){0.f, 0.f, 0.f, 0.f};
    float mr_[4] = {-1e30f, -1e30f, -1e30f, -1e30f};
    float lw[4] = {0.f, 0.f, 0.f, 0.f};

#pragma unroll 1
    for (int c = 0; c < 8; ++c) {
      __syncthreads();                       // VtS/K readers done
      // K chunk: 64 rows x 128 dk = 1024 short8 loads per plane (FIXED)
#pragma unroll
      for (int rep = 0; rep < 4; ++rep) {
        int lin = t + rep * 256;
        int row = lin >> 4, oct = lin & 15;
        size_t g = (segrow + c * 64 + row) * 1024 + h * 128 + oct * 8;
        *(short8*)&KhS[row][oct * 8] = *(const short8*)&Khp[g];
        *(short8*)&KlS[row][oct * 8] = *(const short8*)&Klp[g];
      }
#pragma unroll
      for (int rep = 0; rep < 4; ++rep) {
        int lin = t + rep * 256;
        int dv = lin >> 3, oct = lin & 7;
        *(short8*)&VtS[dv][oct * 8] =
            *(const short8*)&VTp[((size_t)bh * 128 + dv) * 8192 +
                                 (size_t)seg * 512 + c * 64 + oct * 8];
      }
      __syncthreads();

      // QK^T: 4 key-blocks x 4 ksteps x (hh, hl, lh)
      f32x4 sblk[4];
#pragma unroll
      for (int kb = 0; kb < 4; ++kb) sblk[kb] = (f32x4){0.f, 0.f, 0.f, 0.f};
#pragma unroll
      for (int kb = 0; kb < 4; ++kb) {
#pragma unroll
        for (int ksv = 0; ksv < 4; ++ksv) {
          short8 bh_ = *(const short8*)&KhS[kb * 16 + lr][ksv * 32 + lg * 8];
          short8 bl_ = *(const short8*)&KlS[kb * 16 + lr][ksv * 32 + lg * 8];
          sblk[kb] = __builtin_amdgcn_mfma_f32_16x16x32_bf16(ah[ksv], bh_, sblk[kb], 0, 0, 0);
          sblk[kb] = __builtin_amdgcn_mfma_f32_16x16x32_bf16(ah[ksv], bl_, sblk[kb], 0, 0, 0);
          sblk[kb] = __builtin_amdgcn_mfma_f32_16x16x32_bf16(al[ksv], bh_, sblk[kb], 0, 0, 0);
        }
      }
      // register online softmax (rows lg*4+r, cols lr+16*kb)
      float fsc[4];
#pragma unroll
      for (int r = 0; r < 4; ++r) {
        float s0 = sblk[0][r] * scale, s1 = sblk[1][r] * scale;
        float s2 = sblk[2][r] * scale, s3 = sblk[3][r] * scale;
        float cmax = fmaxf(fmaxf(s0, s1), fmaxf(s2, s3));
        cmax = fmaxf(cmax, __shfl_xor(cmax, 1));
        cmax = fmaxf(cmax, __shfl_xor(cmax, 2));
        cmax = fmaxf(cmax, __shfl_xor(cmax, 4));
        cmax = fmaxf(cmax, __shfl_xor(cmax, 8));
        float mnew = fmaxf(mr_[r], cmax);
        float f = __expf(mr_[r] - mnew);
        float p0 = __expf(s0 - mnew), p1 = __expf(s1 - mnew);
        float p2 = __expf(s2 - mnew), p3 = __expf(s3 - mnew);
        float ps = p0 + p1 + p2 + p3;
        ps += __shfl_xor(ps, 1);
        ps += __shfl_xor(ps, 2);
        ps += __shfl_xor(ps, 4);
        ps += __shfl_xor(ps, 8);
        lw[r] = lw[r] * f + ps;
        mr_[r] = mnew;
        fsc[r] = f;
        int prow = wave * 16 + lg * 4 + r;
        *(unsigned short*)&Ps[prow][lr] = f2bf(p0);
        *(unsigned short*)&Ps[prow][lr + 16] = f2bf(p1);
        *(unsigned short*)&Ps[prow][lr + 32] = f2bf(p2);
        *(unsigned short*)&Ps[prow][lr + 48] = f2bf(p3);
      }
#pragma unroll
      for (int vb = 0; vb < 8; ++vb) {
        o[vb][0] *= fsc[0]; o[vb][1] *= fsc[1];
        o[vb][2] *= fsc[2]; o[vb][3] *= fsc[3];
      }
      // PV (P via LDS layout-hop; V single bf16)
      short8 pa0 = *(const short8*)&Ps[wave * 16 + lr][lg * 8];
      short8 pa1 = *(const short8*)&Ps[wave * 16 + lr][lg * 8 + 32];
#pragma unroll
      for (int vb = 0; vb < 8; ++vb) {
        short8 b0 = *(const short8*)&VtS[vb * 16 + lr][lg * 8];
        short8 b1 = *(const short8*)&VtS[vb * 16 + lr][lg * 8 + 32];
        o[vb] = __builtin_amdgcn_mfma_f32_16x16x32_bf16(pa0, b0, o[vb], 0, 0, 0);
        o[vb] = __builtin_amdgcn_mfma_f32_16x16x32_bf16(pa1, b1, o[vb], 0, 0, 0);
      }
    }
    {
      float clr[4];
#pragma unroll
      for (int r = 0; r < 4; ++r) clr[r] = wdot / lw[r];
#pragma unroll
      for (int vb = 0; vb < 8; ++vb) {
        accum[vb][0] += clr[0] * o[vb][0];
        accum[vb][1] += clr[1] * o[vb][1];
        accum[vb][2] += clr[2] * o[vb][2];
        accum[vb][3] += clr[3] * o[vb][3];
      }
    }
  }

  // ---- write out: rows wave*16+lg*4+r, cols vb*16+lr ----
#pragma unroll
  for (int vb = 0; vb < 8; ++vb)
#pragma unroll
    for (int r = 0; r < 4; ++r) {
      size_t row = segrow + rb * 64 + wave * 16 + lg * 4 + r;
      Out[row * 128 + vb * 16 + lr] = accum[vb][r];
    }
}

// ---------------------------------------------------------------------------
extern "C" void kernel_launch(void* const* d_in, const int* in_sizes, int n_in,
                              void* d_out, int out_size, void* d_ws, size_t ws_size,
                              hipStream_t stream) {
  (void)in_sizes; (void)n_in; (void)out_size; (void)ws_size;
  const float* x    = (const float*)d_in[0];
  const float* wq   = (const float*)d_in[1];
  const float* bq   = (const float*)d_in[2];
  const float* wk   = (const float*)d_in[3];
  const float* bk   = (const float*)d_in[4];
  const float* wv   = (const float*)d_in[5];
  const float* bv   = (const float*)d_in[6];
  const float* beta = (const float*)d_in[7];
  float* Out = (float*)d_out;

  // ws: Qh|Ql|Kh|Kl|VT (bf16 planes) | MT bf16 | MemST f32 | Zs f32 | W splits
  const size_t PL = (size_t)BS_ * 1024;
  __hip_bfloat16* Qhp = (__hip_bfloat16*)d_ws;
  __hip_bfloat16* Qlp = Qhp + PL;
  __hip_bfloat16* Khp = Qlp + PL;
  __hip_bfloat16* Klp = Khp + PL;
  __hip_bfloat16* VTp = Klp + PL;
  __hip_bfloat16* MT  = VTp + PL;
  float* MemST = (float*)(MT + (size_t)NSEG_ * 32 * 16384);
  float* Zs = MemST + (size_t)NSEG_ * 32 * 16384;
  __hip_bfloat16* Wt = (__hip_bfloat16*)(Zs + (size_t)NSEG_ * 32 * 128);
  const size_t WSZ = (size_t)1024 * 1024;
  __hip_bfloat16* Wqh = Wt;
  __hip_bfloat16* Wql = Wqh + WSZ;
  __hip_bfloat16* Wkh = Wql + WSZ;
  __hip_bfloat16* Wkl = Wkh + WSZ;
  __hip_bfloat16* Wvh = Wkl + WSZ;
  __hip_bfloat16* Wvl = Wvh + WSZ;

  dim3 b256(256);
  dim3 gp(32, 32);
  prep_w<<<gp, b256, 0, stream>>>(wq, Wqh, Wql);
  prep_w<<<gp, b256, 0, stream>>>(wk, Wkh, Wkl);
  prep_w<<<gp, b256, 0, stream>>>(wv, Wvh, Wvl);

  dim3 gg(256, 8);
  gemm_bf16x3<0><<<gg, b256, 0, stream>>>(x, Wqh, Wql, bq, Qhp, Qlp);
  gemm_bf16x3<0><<<gg, b256, 0, stream>>>(x, Wkh, Wkl, bk, Khp, Klp);
  gemm_bf16x3<1><<<gg, b256, 0, stream>>>(x, Wvh, Wvl, bv, VTp, nullptr);

  seg_kv<<<512, b256, 0, stream>>>(Khp, Klp, VTp, MemST, Zs);
  prefix_scan<<<512, b256, 0, stream>>>(MemST, MT, Zs);
  attn_blend_mfma<<<dim3(8, 16, 4), b256, 0, stream>>>(
      Qhp, Qlp, Khp, Klp, VTp, MT, Zs, beta, Out);
}

// Round 6
// 1685.718 us; speedup vs baseline: 3.7062x; 1.0255x over previous
//
#include <hip/hip_runtime.h>
#include <hip/hip_bf16.h>

#define B_    4
#define S_    8192
#define D_    1024
#define H_    8
#define DKV_  128
#define SEG_  512
#define NSEG_ 16
#define BS_   (B_ * S_)   // 32768

typedef __attribute__((ext_vector_type(8))) short short8;
typedef __attribute__((ext_vector_type(4))) float f32x4;

__device__ inline float bf2f(unsigned short u) {
  unsigned int x = ((unsigned int)u) << 16;
  return __uint_as_float(x);
}
__device__ inline unsigned short f2bf(float f) {
  __hip_bfloat16 h = __float2bfloat16(f);
  return *(unsigned short*)&h;
}
__device__ inline void bf16split(float f, unsigned short& hi, unsigned short& lo) {
  __hip_bfloat16 h = __float2bfloat16(f);
  float hf = __bfloat162float(h);
  __hip_bfloat16 l = __float2bfloat16(f - hf);
  hi = *(unsigned short*)&h;
  lo = *(unsigned short*)&l;
}

// ---------------------------------------------------------------------------
// P0: W f32 [K][N] -> Wt_hi/Wt_lo bf16 [N][K] (transposed + split)
// ---------------------------------------------------------------------------
__global__ __launch_bounds__(256) void prep_w(
    const float* __restrict__ W, __hip_bfloat16* __restrict__ Whi,
    __hip_bfloat16* __restrict__ Wlo) {
  __shared__ float tile[32][33];
  const int k0 = blockIdx.x * 32, n0 = blockIdx.y * 32;
  const int tx = threadIdx.x & 31, ty = threadIdx.x >> 5;
#pragma unroll
  for (int r = 0; r < 4; ++r) {
    int k = ty + r * 8;
    tile[k][tx] = W[(size_t)(k0 + k) * 1024 + n0 + tx];
  }
  __syncthreads();
#pragma unroll
  for (int r = 0; r < 4; ++r) {
    int n = ty + r * 8;
    float v = tile[tx][n];
    unsigned short hb, lb;
    bf16split(v, hb, lb);
    *(unsigned short*)&Whi[(size_t)(n0 + n) * 1024 + k0 + tx] = hb;
    *(unsigned short*)&Wlo[(size_t)(n0 + n) * 1024 + k0 + tx] = lb;
  }
}

// ---------------------------------------------------------------------------
// P1: x f32 -> Ah/Al bf16 planes (one pass; removes per-GEMM split VALU work)
// ---------------------------------------------------------------------------
__global__ __launch_bounds__(256) void split_x(
    const float* __restrict__ X, __hip_bfloat16* __restrict__ Ah,
    __hip_bfloat16* __restrict__ Al) {
  const size_t n4 = (size_t)BS_ * 1024 / 4;
  for (size_t idx = (size_t)blockIdx.x * 256 + threadIdx.x; idx < n4;
       idx += (size_t)gridDim.x * 256) {
    float4 v = *(const float4*)&X[idx * 4];
    ushort4 hv, lv;
    bf16split(v.x, hv.x, lv.x);
    bf16split(v.y, hv.y, lv.y);
    bf16split(v.z, hv.z, lv.z);
    bf16split(v.w, hv.w, lv.w);
    *(ushort4*)&Ah[idx * 4] = hv;
    *(ushort4*)&Al[idx * 4] = lv;
  }
}

// ---------------------------------------------------------------------------
// K1: Y = A @ W + bias via MFMA bf16x3.
// PRE=1: A from pre-split bf16 planes (pure copy staging).
// PRE=0: A from f32 x with inline split (fallback when ws too small).
// MODE 0: write hi/lo bf16 planes [m][1024] (Q, K).
// MODE 1: write single-bf16 transposed plane VT[((b*8+h)*128+dv)*8192 + s].
// 1-D grid 2048: nb = wgid&7 (XCD-resident W block), mb = wgid>>3.
// ---------------------------------------------------------------------------
template <int MODE, int PRE>
__global__ __launch_bounds__(256) void gemm_bf16x3(
    const float* __restrict__ Af, const __hip_bfloat16* __restrict__ Ahp,
    const __hip_bfloat16* __restrict__ Alp,
    const __hip_bfloat16* __restrict__ Bhg, const __hip_bfloat16* __restrict__ Blg,
    const float* __restrict__ bias,
    __hip_bfloat16* __restrict__ Oh, __hip_bfloat16* __restrict__ Ol) {
  __shared__ __hip_bfloat16 Ah[128][40];
  __shared__ __hip_bfloat16 Al[128][40];
  __shared__ __hip_bfloat16 Bh[128][40];
  __shared__ __hip_bfloat16 Bl[128][40];
  const int t = threadIdx.x;
  const int wgid = blockIdx.x;
  const int m0 = (wgid >> 3) * 128, n0 = (wgid & 7) * 128;
  const int wave = t >> 6, lane = t & 63;
  const int wm = (wave >> 1) * 64, wn = (wave & 1) * 64;
  const int lr = lane & 15, ks = lane >> 4;

  f32x4 acc[4][4];
#pragma unroll
  for (int i = 0; i < 4; ++i)
#pragma unroll
    for (int j = 0; j < 4; ++j) acc[i][j] = (f32x4){0.f, 0.f, 0.f, 0.f};

  for (int k0 = 0; k0 < 1024; k0 += 32) {
    __syncthreads();
    if (PRE) {
#pragma unroll
      for (int rep = 0; rep < 2; ++rep) {
        int lin = t + rep * 256;               // 0..511
        int row = lin >> 2, kq = (lin & 3) * 8;
        *(uint4*)&Ah[row][kq] =
            *(const uint4*)&Ahp[(size_t)(m0 + row) * 1024 + k0 + kq];
        *(uint4*)&Al[row][kq] =
            *(const uint4*)&Alp[(size_t)(m0 + row) * 1024 + k0 + kq];
      }
    } else {
#pragma unroll
      for (int rep = 0; rep < 4; ++rep) {
        int lin = t + rep * 256;
        int row = lin >> 3, kq = (lin & 7) * 4;
        float4 v = *(const float4*)&Af[(size_t)(m0 + row) * 1024 + k0 + kq];
        ushort4 hv, lv;
        bf16split(v.x, hv.x, lv.x);
        bf16split(v.y, hv.y, lv.y);
        bf16split(v.z, hv.z, lv.z);
        bf16split(v.w, hv.w, lv.w);
        *(ushort4*)&Ah[row][kq] = hv;
        *(ushort4*)&Al[row][kq] = lv;
      }
    }
#pragma unroll
    for (int rep = 0; rep < 2; ++rep) {
      int lin = t + rep * 256;
      int row = lin >> 2, kq = (lin & 3) * 8;
      *(uint4*)&Bh[row][kq] =
          *(const uint4*)&Bhg[(size_t)(n0 + row) * 1024 + k0 + kq];
      *(uint4*)&Bl[row][kq] =
          *(const uint4*)&Blg[(size_t)(n0 + row) * 1024 + k0 + kq];
    }
    __syncthreads();

    short8 afh[4], afl[4];
#pragma unroll
    for (int fm = 0; fm < 4; ++fm) {
      afh[fm] = *(short8*)&Ah[wm + fm * 16 + lr][ks * 8];
      afl[fm] = *(short8*)&Al[wm + fm * 16 + lr][ks * 8];
    }
#pragma unroll
    for (int fn = 0; fn < 4; ++fn) {
      short8 bfh = *(short8*)&Bh[wn + fn * 16 + lr][ks * 8];
      short8 bfl = *(short8*)&Bl[wn + fn * 16 + lr][ks * 8];
#pragma unroll
      for (int fm = 0; fm < 4; ++fm) {
        acc[fm][fn] = __builtin_amdgcn_mfma_f32_16x16x32_bf16(afh[fm], bfh, acc[fm][fn], 0, 0, 0);
        acc[fm][fn] = __builtin_amdgcn_mfma_f32_16x16x32_bf16(afh[fm], bfl, acc[fm][fn], 0, 0, 0);
        acc[fm][fn] = __builtin_amdgcn_mfma_f32_16x16x32_bf16(afl[fm], bfh, acc[fm][fn], 0, 0, 0);
      }
    }
  }
  // epilogue: C layout col=lane&15, row=(lane>>4)*4+reg  [HW-verified]
#pragma unroll
  for (int fn = 0; fn < 4; ++fn) {
    int n = n0 + wn + fn * 16 + lr;
    float bv = bias[n];
#pragma unroll
    for (int fm = 0; fm < 4; ++fm) {
      int mrow = m0 + wm + fm * 16 + ks * 4;
      if (MODE == 0) {
#pragma unroll
        for (int r = 0; r < 4; ++r) {
          float val = acc[fm][fn][r] + bv;
          unsigned short hb, lb;
          bf16split(val, hb, lb);
          *(unsigned short*)&Oh[(size_t)(mrow + r) * 1024 + n] = hb;
          *(unsigned short*)&Ol[(size_t)(mrow + r) * 1024 + n] = lb;
        }
      } else {
        int bb = mrow >> 13, s = mrow & 8191;
        size_t vtix = (((size_t)(bb * 8 + (n >> 7))) * 128 + (n & 127)) * 8192 + s;
        ushort4 pk;
        pk.x = f2bf(acc[fm][fn][0] + bv);
        pk.y = f2bf(acc[fm][fn][1] + bv);
        pk.z = f2bf(acc[fm][fn][2] + bv);
        pk.w = f2bf(acc[fm][fn][3] + bv);
        *(ushort4*)&Oh[vtix] = pk;
      }
    }
  }
}

// ---------------------------------------------------------------------------
// K2: per-(seg,b,h) state: SkvT[dv][dk] = sum_l v[l][dv]*sk[l][dk] (f32),
//     Zs[dk] = (sum_l sk[l][dk]) * SEG.  sk=elu(k)+1, k = Kh+Kl, v from VT.
// V tile transposed back to row-major during LDS write (conflict-free reads).
// ---------------------------------------------------------------------------
__global__ __launch_bounds__(256) void seg_kv(
    const __hip_bfloat16* __restrict__ Khp, const __hip_bfloat16* __restrict__ Klp,
    const __hip_bfloat16* __restrict__ VTp, float* __restrict__ MemST,
    float* __restrict__ Zs) {
  __shared__ float sk[16][132];
  __shared__ float sv[16][132];
  const int bx = blockIdx.x;
  const int seg = bx >> 5, bh = bx & 31;
  const int b = bh >> 3, h = bh & 7;
  const int t = threadIdx.x;
  const int tr = t >> 4, tc = t & 15;    // dv0 = tr*8, dk0 = tc*8
  float acc[8][8] = {};
  float zacc = 0.f;
  const size_t rowbase = (size_t)b * S_ + (size_t)seg * SEG_;
  const size_t sbase = (size_t)seg * SEG_;
  const size_t vtbase = (size_t)(b * 8 + h) * 128 * 8192;
  for (int l0 = 0; l0 < SEG_; l0 += 16) {
    __syncthreads();
    {
      int row = t >> 4, oct = t & 15;
      size_t g = (rowbase + l0 + row) * 1024 + h * 128 + oct * 8;
      short8 hv = *(const short8*)&Khp[g];
      short8 lv = *(const short8*)&Klp[g];
#pragma unroll
      for (int e = 0; e < 8; ++e) {
        float kvf = bf2f((unsigned short)hv[e]) + bf2f((unsigned short)lv[e]);
        sk[row][oct * 8 + e] = kvf > 0.f ? kvf + 1.f : __expf(kvf);
      }
      int dv = t >> 1, half = t & 1;
      short8 vv = *(const short8*)&VTp[vtbase + (size_t)dv * 8192 + sbase + l0 + half * 8];
#pragma unroll
      for (int e = 0; e < 8; ++e) sv[half * 8 + e][dv] = bf2f((unsigned short)vv[e]);
    }
    __syncthreads();
#pragma unroll
    for (int l = 0; l < 16; ++l) {
      float a[8], kk[8];
      *(float4*)&a[0] = *(const float4*)&sv[l][tr * 8];
      *(float4*)&a[4] = *(const float4*)&sv[l][tr * 8 + 4];
      *(float4*)&kk[0] = *(const float4*)&sk[l][tc * 8];
      *(float4*)&kk[4] = *(const float4*)&sk[l][tc * 8 + 4];
#pragma unroll
      for (int i = 0; i < 8; ++i)
#pragma unroll
        for (int j = 0; j < 8; ++j)
          acc[i][j] = fmaf(a[i], kk[j], acc[i][j]);
    }
    if (t < 128) {
#pragma unroll
      for (int l = 0; l < 16; ++l) zacc += sk[l][t];
    }
  }
  const size_t base = ((size_t)seg * 32 + bh) * 16384;
#pragma unroll
  for (int i = 0; i < 8; ++i)
#pragma unroll
    for (int j = 0; j < 8; j += 4) {
      float4 o = {acc[i][j], acc[i][j + 1], acc[i][j + 2], acc[i][j + 3]};
      *(float4*)&MemST[base + (size_t)(tr * 8 + i) * 128 + tc * 8 + j] = o;
    }
  if (t < 128) Zs[((size_t)seg * 32 + bh) * 128 + t] = zacc * (float)SEG_;
}

// ---------------------------------------------------------------------------
// K3: inclusive prefix over segments; also emits bf16 MemT plane.
// ---------------------------------------------------------------------------
__global__ __launch_bounds__(256) void prefix_scan(
    float* __restrict__ Mem, __hip_bfloat16* __restrict__ MT,
    float* __restrict__ Zs) {
  const int bx = blockIdx.x;
  const int bh = bx & 31;
  const int part = bx >> 5;
  const int t = threadIdx.x;
  for (int jj = 0; jj < 4; ++jj) {
    size_t flat = ((size_t)part * 4 + jj) * 256 + t;
    float run = 0.f;
#pragma unroll
    for (int seg = 0; seg < NSEG_; ++seg) {
      size_t idx = ((size_t)seg * 32 + bh) * 16384 + flat;
      run += Mem[idx];
      Mem[idx] = run;
      *(unsigned short*)&MT[idx] = f2bf(run);
    }
  }
  if (part == 0 && t < 128) {
    float run = 0.f;
#pragma unroll
    for (int seg = 0; seg < NSEG_; ++seg) {
      size_t idx = ((size_t)seg * 32 + bh) * 128 + t;
      run += Zs[idx];
      Zs[idx] = run;
    }
  }
}

// ---------------------------------------------------------------------------
// K4 v4: MFMA flash attention + retrieval.  1-D grid 512 with XCD swizzle:
// wgid = rb*64 + segb  ->  XCD = wgid%8 = segb%8, so all 8 rb-blocks sharing
// a (seg,b)'s K/V/Mem land on the SAME XCD L2 (was: 8 different XCDs).
// ---------------------------------------------------------------------------
__global__ __launch_bounds__(256, 2) void attn_blend_mfma(
    const __hip_bfloat16* __restrict__ Qhp, const __hip_bfloat16* __restrict__ Qlp,
    const __hip_bfloat16* __restrict__ Khp, const __hip_bfloat16* __restrict__ Klp,
    const __hip_bfloat16* __restrict__ VTp, const __hip_bfloat16* __restrict__ MT,
    const float* __restrict__ Zs, const float* __restrict__ beta,
    float* __restrict__ Out) {
  __shared__ __hip_bfloat16 KhS[64][136];
  __shared__ __hip_bfloat16 KlS[64][136];
  __shared__ __hip_bfloat16 VtS[128][72];   // V^T chunk / MemT chunk
  __shared__ __hip_bfloat16 Ps[64][72];     // P (per-wave 16-row slabs)
  __shared__ float zl[128];

  const int t = threadIdx.x;
  const int wgid = blockIdx.x;
  const int rb = wgid >> 6;            // 0..7
  const int segb = wgid & 63;          // 0..63 -> XCD = segb%8
  const int seg = segb & 15, b = segb >> 4;
  const int wave = t >> 6, lane = t & 63;
  const int lr = lane & 15, lg = lane >> 4;
  const float scale = 0.08838834764831845f;  // 1/sqrt(128)
  const float bsig = 1.f / (1.f + __expf(-beta[0]));
  const float wmem = bsig * 0.125f, wdot = (1.f - bsig) * 0.125f;

  const size_t segrow = (size_t)b * S_ + (size_t)seg * SEG_;
  const int qrow = rb * 64 + wave * 16 + lr;          // A-fragment row
  const size_t qbase = (segrow + qrow) * 1024;

  f32x4 accum[8];
#pragma unroll
  for (int v = 0; v < 8; ++v) accum[v] = (f32x4){0.f, 0.f, 0.f, 0.f};

  for (int h = 0; h < H_; ++h) {
    const int bh = b * 8 + h;
    __syncthreads();                         // prev head fully done
    if (t < 128) zl[t] = Zs[((size_t)seg * 32 + bh) * 128 + t];

    // ---- Q fragments (hi/lo) ----
    short8 ah[4], al[4];
#pragma unroll
    for (int ksv = 0; ksv < 4; ++ksv) {
      size_t off = qbase + h * 128 + lg * 8 + ksv * 32;
      ah[ksv] = *(const short8*)&Qhp[off];
      al[ksv] = *(const short8*)&Qlp[off];
    }

    // ---- sq = elu(q)+1: bf16 frags + f32 stash ----
    short8 sqf[4];
    f32x4 sqa[4], sqb[4];
#pragma unroll
    for (int ksv = 0; ksv < 4; ++ksv) {
#pragma unroll
      for (int e = 0; e < 8; ++e) {
        float q = bf2f((unsigned short)ah[ksv][e]) + bf2f((unsigned short)al[ksv][e]);
        float s = q > 0.f ? q + 1.f : __expf(q);
        if (e < 4) sqa[ksv][e] = s; else sqb[ksv][e - 4] = s;
        sqf[ksv][e] = (short)f2bf(s);
      }
    }
    __syncthreads();                         // zl visible

    // ---- denominator: (sq . z) for row lr ----
    float dnm;
    {
      float part = 0.f;
#pragma unroll
      for (int ksv = 0; ksv < 4; ++ksv) {
        float4 z0 = *(const float4*)&zl[lg * 8 + ksv * 32];
        float4 z1 = *(const float4*)&zl[lg * 8 + ksv * 32 + 4];
        part += sqa[ksv][0] * z0.x + sqa[ksv][1] * z0.y + sqa[ksv][2] * z0.z +
                sqa[ksv][3] * z0.w + sqb[ksv][0] * z1.x + sqb[ksv][1] * z1.y +
                sqb[ksv][2] * z1.z + sqb[ksv][3] * z1.w;
      }
      part += __shfl_xor(part, 16);
      part += __shfl_xor(part, 32);
      dnm = part + 1e-5f;
    }

    // ---- retrieval: pm = sq @ MemT ----
    f32x4 pm[8];
#pragma unroll
    for (int v = 0; v < 8; ++v) pm[v] = (f32x4){0.f, 0.f, 0.f, 0.f};
    const size_t mtbase = ((size_t)seg * 32 + bh) * 16384;
#pragma unroll 1
    for (int mc = 0; mc < 2; ++mc) {
      if (mc) __syncthreads();
#pragma unroll
      for (int rep = 0; rep < 4; ++rep) {
        int lin = t + rep * 256;
        int dv = lin >> 3, oct = lin & 7;
        *(short8*)&VtS[dv][oct * 8] =
            *(const short8*)&MT[mtbase + (size_t)dv * 128 + mc * 64 + oct * 8];
      }
      __syncthreads();
#pragma unroll
      for (int ks2 = 0; ks2 < 2; ++ks2) {
        short8 af = sqf[mc * 2 + ks2];
#pragma unroll
        for (int vb = 0; vb < 8; ++vb) {
          short8 bf = *(const short8*)&VtS[vb * 16 + lr][ks2 * 32 + lg * 8];
          pm[vb] = __builtin_amdgcn_mfma_f32_16x16x32_bf16(af, bf, pm[vb], 0, 0, 0);
        }
      }
    }
    {
      float cdr[4];
#pragma unroll
      for (int r = 0; r < 4; ++r) cdr[r] = wmem / __shfl(dnm, lg * 4 + r);
#pragma unroll
      for (int vb = 0; vb < 8; ++vb) {
        accum[vb][0] += cdr[0] * pm[vb][0];
        accum[vb][1] += cdr[1] * pm[vb][1];
        accum[vb][2] += cdr[2] * pm[vb][2];
        accum[vb][3] += cdr[3] * pm[vb][3];
      }
    }

    // ---- local softmax attention over 8 chunks of 64 keys ----
    f32x4 o[8];
#pragma unroll
    for (int v = 0; v < 8; ++v) o[v] = (f32x4){0.f, 0.f, 0.f, 0.f};
    float mr_[4] = {-1e30f, -1e30f, -1e30f, -1e30f};
    float lw[4] = {0.f, 0.f, 0.f, 0.f};

#pragma unroll 1
    for (int c = 0; c < 8; ++c) {
      __syncthreads();                       // VtS/K readers done
      // K chunk: 64 rows x 128 dk = 1024 short8 loads per plane
#pragma unroll
      for (int rep = 0; rep < 4; ++rep) {
        int lin = t + rep * 256;
        int row = lin >> 4, oct = lin & 15;
        size_t g = (segrow + c * 64 + row) * 1024 + h * 128 + oct * 8;
        *(short8*)&KhS[row][oct * 8] = *(const short8*)&Khp[g];
        *(short8*)&KlS[row][oct * 8] = *(const short8*)&Klp[g];
      }
#pragma unroll
      for (int rep = 0; rep < 4; ++rep) {
        int lin = t + rep * 256;
        int dv = lin >> 3, oct = lin & 7;
        *(short8*)&VtS[dv][oct * 8] =
            *(const short8*)&VTp[((size_t)bh * 128 + dv) * 8192 +
                                 (size_t)seg * 512 + c * 64 + oct * 8];
      }
      __syncthreads();

      // QK^T: 4 key-blocks x 4 ksteps x (hh, hl, lh)
      f32x4 sblk[4];
#pragma unroll
      for (int kb = 0; kb < 4; ++kb) sblk[kb] = (f32x4){0.f, 0.f, 0.f, 0.f};
#pragma unroll
      for (int kb = 0; kb < 4; ++kb) {
#pragma unroll
        for (int ksv = 0; ksv < 4; ++ksv) {
          short8 bh_ = *(const short8*)&KhS[kb * 16 + lr][ksv * 32 + lg * 8];
          short8 bl_ = *(const short8*)&KlS[kb * 16 + lr][ksv * 32 + lg * 8];
          sblk[kb] = __builtin_amdgcn_mfma_f32_16x16x32_bf16(ah[ksv], bh_, sblk[kb], 0, 0, 0);
          sblk[kb] = __builtin_amdgcn_mfma_f32_16x16x32_bf16(ah[ksv], bl_, sblk[kb], 0, 0, 0);
          sblk[kb] = __builtin_amdgcn_mfma_f32_16x16x32_bf16(al[ksv], bh_, sblk[kb], 0, 0, 0);
        }
      }
      // register online softmax (rows lg*4+r, cols lr+16*kb)
      float fsc[4];
#pragma unroll
      for (int r = 0; r < 4; ++r) {
        float s0 = sblk[0][r] * scale, s1 = sblk[1][r] * scale;
        float s2 = sblk[2][r] * scale, s3 = sblk[3][r] * scale;
        float cmax = fmaxf(fmaxf(s0, s1), fmaxf(s2, s3));
        cmax = fmaxf(cmax, __shfl_xor(cmax, 1));
        cmax = fmaxf(cmax, __shfl_xor(cmax, 2));
        cmax = fmaxf(cmax, __shfl_xor(cmax, 4));
        cmax = fmaxf(cmax, __shfl_xor(cmax, 8));
        float mnew = fmaxf(mr_[r], cmax);
        float f = __expf(mr_[r] - mnew);
        float p0 = __expf(s0 - mnew), p1 = __expf(s1 - mnew);
        float p2 = __expf(s2 - mnew), p3 = __expf(s3 - mnew);
        float ps = p0 + p1 + p2 + p3;
        ps += __shfl_xor(ps, 1);
        ps += __shfl_xor(ps, 2);
        ps += __shfl_xor(ps, 4);
        ps += __shfl_xor(ps, 8);
        lw[r] = lw[r] * f + ps;
        mr_[r] = mnew;
        fsc[r] = f;
        int prow = wave * 16 + lg * 4 + r;
        *(unsigned short*)&Ps[prow][lr] = f2bf(p0);
        *(unsigned short*)&Ps[prow][lr + 16] = f2bf(p1);
        *(unsigned short*)&Ps[prow][lr + 32] = f2bf(p2);
        *(unsigned short*)&Ps[prow][lr + 48] = f2bf(p3);
      }
#pragma unroll
      for (int vb = 0; vb < 8; ++vb) {
        o[vb][0] *= fsc[0]; o[vb][1] *= fsc[1];
        o[vb][2] *= fsc[2]; o[vb][3] *= fsc[3];
      }
      // PV (P via LDS layout-hop; V single bf16)
      short8 pa0 = *(const short8*)&Ps[wave * 16 + lr][lg * 8];
      short8 pa1 = *(const short8*)&Ps[wave * 16 + lr][lg * 8 + 32];
#pragma unroll
      for (int vb = 0; vb < 8; ++vb) {
        short8 b0 = *(const short8*)&VtS[vb * 16 + lr][lg * 8];
        short8 b1 = *(const short8*)&VtS[vb * 16 + lr][lg * 8 + 32];
        o[vb] = __builtin_amdgcn_mfma_f32_16x16x32_bf16(pa0, b0, o[vb], 0, 0, 0);
        o[vb] = __builtin_amdgcn_mfma_f32_16x16x32_bf16(pa1, b1, o[vb], 0, 0, 0);
      }
    }
    {
      float clr[4];
#pragma unroll
      for (int r = 0; r < 4; ++r) clr[r] = wdot / lw[r];
#pragma unroll
      for (int vb = 0; vb < 8; ++vb) {
        accum[vb][0] += clr[0] * o[vb][0];
        accum[vb][1] += clr[1] * o[vb][1];
        accum[vb][2] += clr[2] * o[vb][2];
        accum[vb][3] += clr[3] * o[vb][3];
      }
    }
  }

  // ---- write out: rows wave*16+lg*4+r, cols vb*16+lr ----
#pragma unroll
  for (int vb = 0; vb < 8; ++vb)
#pragma unroll
    for (int r = 0; r < 4; ++r) {
      size_t row = segrow + rb * 64 + wave * 16 + lg * 4 + r;
      Out[row * 128 + vb * 16 + lr] = accum[vb][r];
    }
}

// ---------------------------------------------------------------------------
extern "C" void kernel_launch(void* const* d_in, const int* in_sizes, int n_in,
                              void* d_out, int out_size, void* d_ws, size_t ws_size,
                              hipStream_t stream) {
  (void)in_sizes; (void)n_in; (void)out_size;
  const float* x    = (const float*)d_in[0];
  const float* wq   = (const float*)d_in[1];
  const float* bq   = (const float*)d_in[2];
  const float* wk   = (const float*)d_in[3];
  const float* bk   = (const float*)d_in[4];
  const float* wv   = (const float*)d_in[5];
  const float* bv   = (const float*)d_in[6];
  const float* beta = (const float*)d_in[7];
  float* Out = (float*)d_out;

  // ws layout:
  //   Qh | Ql | Kh | Kl | VT (5 bf16 planes, 67.1 MB each)
  //   region1 union:
  //     during GEMMs (split path): Ahp | Alp (134 MB)
  //     after GEMMs:               MT (16.8) | MemST (33.6) | Zs (0.26)
  //   W splits (12.6 MB)
  const size_t PL = (size_t)BS_ * 1024;            // plane elements
  const size_t PLb = PL * 2;                       // plane bytes (bf16)
  const size_t MEMN = (size_t)NSEG_ * 32 * 16384;  // Mem elements
  char* p = (char*)d_ws;
  __hip_bfloat16* Qhp = (__hip_bfloat16*)p;          p += PLb;
  __hip_bfloat16* Qlp = (__hip_bfloat16*)p;          p += PLb;
  __hip_bfloat16* Khp = (__hip_bfloat16*)p;          p += PLb;
  __hip_bfloat16* Klp = (__hip_bfloat16*)p;          p += PLb;
  __hip_bfloat16* VTp = (__hip_bfloat16*)p;          p += PLb;
  char* r1 = p;
  __hip_bfloat16* MT  = (__hip_bfloat16*)r1;
  float* MemST = (float*)(r1 + MEMN * 2);
  float* Zs    = (float*)(r1 + MEMN * 2 + MEMN * 4);
  const size_t aliasB = MEMN * 2 + MEMN * 4 + (size_t)NSEG_ * 32 * 128 * 4;
  __hip_bfloat16* Ahp = (__hip_bfloat16*)r1;         // alias (split path only)
  __hip_bfloat16* Alp = Ahp + PL;
  const size_t WSZ = (size_t)1024 * 1024;
  // decide path by available scratch
  const size_t need_split  = 5 * PLb + 2 * PLb + 6 * WSZ * 2;
  bool use_split = (ws_size >= need_split);
  size_t r1sz = use_split ? (2 * PLb) : aliasB;
  if (!use_split && aliasB < 2 * PLb) r1sz = aliasB;  // compact fallback
  __hip_bfloat16* Wt = (__hip_bfloat16*)(r1 + (use_split ? 2 * PLb : aliasB));
  __hip_bfloat16* Wqh = Wt;
  __hip_bfloat16* Wql = Wqh + WSZ;
  __hip_bfloat16* Wkh = Wql + WSZ;
  __hip_bfloat16* Wkl = Wkh + WSZ;
  __hip_bfloat16* Wvh = Wkl + WSZ;
  __hip_bfloat16* Wvl = Wvh + WSZ;
  (void)r1sz;

  dim3 b256(256);
  dim3 gp(32, 32);
  prep_w<<<gp, b256, 0, stream>>>(wq, Wqh, Wql);
  prep_w<<<gp, b256, 0, stream>>>(wk, Wkh, Wkl);
  prep_w<<<gp, b256, 0, stream>>>(wv, Wvh, Wvl);

  if (use_split) {
    split_x<<<2048, b256, 0, stream>>>(x, Ahp, Alp);
    gemm_bf16x3<0, 1><<<2048, b256, 0, stream>>>(x, Ahp, Alp, Wqh, Wql, bq, Qhp, Qlp);
    gemm_bf16x3<0, 1><<<2048, b256, 0, stream>>>(x, Ahp, Alp, Wkh, Wkl, bk, Khp, Klp);
    gemm_bf16x3<1, 1><<<2048, b256, 0, stream>>>(x, Ahp, Alp, Wvh, Wvl, bv, VTp, nullptr);
  } else {
    gemm_bf16x3<0, 0><<<2048, b256, 0, stream>>>(x, nullptr, nullptr, Wqh, Wql, bq, Qhp, Qlp);
    gemm_bf16x3<0, 0><<<2048, b256, 0, stream>>>(x, nullptr, nullptr, Wkh, Wkl, bk, Khp, Klp);
    gemm_bf16x3<1, 0><<<2048, b256, 0, stream>>>(x, nullptr, nullptr, Wvh, Wvl, bv, VTp, nullptr);
  }

  seg_kv<<<512, b256, 0, stream>>>(Khp, Klp, VTp, MemST, Zs);
  prefix_scan<<<512, b256, 0, stream>>>(MemST, MT, Zs);
  attn_blend_mfma<<<512, b256, 0, stream>>>(
      Qhp, Qlp, Khp, Klp, VTp, MT, Zs, beta, Out);
}